// Round 5
// baseline (328.444 us; speedup 1.0000x reference)
//
#include <hip/hip_runtime.h>
#include <cstddef>

#define BB 4096
#define DIN 2048
#define RR 7
#define DP 128
#define KK 25
#define DC 16
#define NITERS 3
#define RKH (RR*KK*DC)   // 2800
#define RK  (RR*KK)      // 175
#define KH  (KK*DC)      // 400
#define HD  (RR*DC)      // 112
#define H4  (4*HD)       // 448
#define HEAD_TILES (BB*KK/128)  // 800

typedef __attribute__((ext_vector_type(8))) short bf16x8;
typedef __attribute__((ext_vector_type(4))) float f32x4;

__device__ __forceinline__ unsigned pk_bf16(float a, float b) {
    union { float f; unsigned u; } xa, xb;
    xa.f = a; xb.f = b;
    unsigned ua = (xa.u + 0x7FFFu + ((xa.u >> 16) & 1u)) >> 16;
    unsigned ub = (xb.u + 0x7FFFu + ((xb.u >> 16) & 1u)) >> 16;
    return (ua & 0xFFFFu) | (ub << 16);
}

__device__ __forceinline__ unsigned short bf16_1(float a) {
    union { float f; unsigned u; } xa; xa.f = a;
    return (unsigned short)((xa.u + 0x7FFFu + ((xa.u >> 16) & 1u)) >> 16);
}

// tanh-approx gelu as x * sigmoid(x*(1.5958 + 0.07136 x^2)); fast rcp, no div sequence.
__device__ __forceinline__ float gelu_fast(float x) {
    float u = x * __builtin_fmaf(x * x, 0.07135655f, 1.5957691f);
    u = fmaxf(u, -30.0f);
    float e = __expf(-u);
    return x * __builtin_amdgcn_rcpf(1.0f + e);
}

// ---------------------------------------------------------------------------
// Prep: transpose fp32 [RS][CS] -> bf16 [CS][RS].  (mid-tier only)
// ---------------------------------------------------------------------------
__global__ __launch_bounds__(256) void transpose_cvt_kernel(
    const float* __restrict__ src, unsigned short* __restrict__ dst, int RS, int CS)
{
    __shared__ float T[64][65];
    int r0 = blockIdx.x * 64, c0 = blockIdx.y * 64;
    size_t bo = (size_t)blockIdx.z * RS * CS;
    src += bo; dst += bo;
    int t = threadIdx.x;
    for (int s = t; s < 64 * 16; s += 256) {
        int row = s >> 4, c4 = s & 15;
        int gr = r0 + row, gc = c0 + c4 * 4;
        float4 v = make_float4(0.f, 0.f, 0.f, 0.f);
        if (gr < RS && gc < CS) v = *(const float4*)(src + (size_t)gr * CS + gc);
        T[row][c4 * 4 + 0] = v.x; T[row][c4 * 4 + 1] = v.y;
        T[row][c4 * 4 + 2] = v.z; T[row][c4 * 4 + 3] = v.w;
    }
    __syncthreads();
    for (int s = t; s < 64 * 16; s += 256) {
        int col = s >> 4, r4 = s & 15;
        int gc = c0 + col, gr = r0 + r4 * 4;
        if (gc < CS && gr + 3 < RS) {
            unsigned lo = pk_bf16(T[r4 * 4 + 0][col], T[r4 * 4 + 1][col]);
            unsigned hi = pk_bf16(T[r4 * 4 + 2][col], T[r4 * 4 + 3][col]);
            *(uint2*)(dst + (size_t)gc * RS + gr) = make_uint2(lo, hi);
        }
    }
}

// ---------------------------------------------------------------------------
// Prep: W1 [HD=112][H4=448] fp32 -> fragment-linear bf16 W1F, K zero-padded to 128.
// ---------------------------------------------------------------------------
__global__ __launch_bounds__(256) void w1_frag_kernel(
    const float* __restrict__ W1, unsigned short* __restrict__ W1F)
{
    int d = blockIdx.x * 256 + threadIdx.x;   // dword index
    int e2 = d & 3;
    int lane = (d >> 2) & 63;
    int fid = d >> 8;                          // 0..111
    int j = fid & 3, ks = (fid >> 2) & 3, nc = fid >> 4;
    int col = nc * 64 + j * 16 + (lane & 15);
    int k = ks * 32 + (lane >> 4) * 8 + e2 * 2;
    float a = (k < HD)     ? W1[(size_t)k * H4 + col]       : 0.f;
    float b = (k + 1 < HD) ? W1[(size_t)(k + 1) * H4 + col] : 0.f;
    ((unsigned*)W1F)[d] = pk_bf16(a, b);
}

// ---------------------------------------------------------------------------
// Prep: W_prim [DIN=2048][896] fp32 -> fragment-linear bf16 WPF.
// ---------------------------------------------------------------------------
__global__ __launch_bounds__(256) void wpf_kernel(
    const float* __restrict__ Wp, unsigned short* __restrict__ wpf)
{
    int tid = blockIdx.x * 256 + threadIdx.x;
    int lane = tid & 63;
    int CH = tid >> 6;
    int c = CH & 63, gcol = CH >> 6;
    int n = gcol * 16 + (lane & 15);
    int k0 = c * 32 + (lane >> 4) * 8;
    unsigned d0, d1, d2, d3;
    {
        float a0 = Wp[(size_t)(k0 + 0) * (RR * DP) + n];
        float a1 = Wp[(size_t)(k0 + 1) * (RR * DP) + n];
        float a2 = Wp[(size_t)(k0 + 2) * (RR * DP) + n];
        float a3 = Wp[(size_t)(k0 + 3) * (RR * DP) + n];
        float a4 = Wp[(size_t)(k0 + 4) * (RR * DP) + n];
        float a5 = Wp[(size_t)(k0 + 5) * (RR * DP) + n];
        float a6 = Wp[(size_t)(k0 + 6) * (RR * DP) + n];
        float a7 = Wp[(size_t)(k0 + 7) * (RR * DP) + n];
        d0 = pk_bf16(a0, a1); d1 = pk_bf16(a2, a3);
        d2 = pk_bf16(a4, a5); d3 = pk_bf16(a6, a7);
    }
    *(uint4*)(wpf + (size_t)tid * 8) = make_uint4(d0, d1, d2, d3);
}

// ---------------------------------------------------------------------------
// Prep: w_caps [R][DP][KK][DC] fp32 -> fragment-linear bf16 wcf.
// ---------------------------------------------------------------------------
__global__ __launch_bounds__(256) void wcf_kernel(
    const float* __restrict__ wc, unsigned short* __restrict__ wcf)
{
    __shared__ float Sw[128][17];
    int r = blockIdx.x, nt = blockIdx.y;
    int t = threadIdx.x;
    {
        int d = t >> 1, half = t & 1;
        const float* sp = wc + ((size_t)r * DP + d) * KH + nt * 16 + half * 8;
        float4 v0 = *(const float4*)(sp);
        float4 v1 = *(const float4*)(sp + 4);
        Sw[d][half * 8 + 0] = v0.x; Sw[d][half * 8 + 1] = v0.y;
        Sw[d][half * 8 + 2] = v0.z; Sw[d][half * 8 + 3] = v0.w;
        Sw[d][half * 8 + 4] = v1.x; Sw[d][half * 8 + 5] = v1.y;
        Sw[d][half * 8 + 6] = v1.z; Sw[d][half * 8 + 7] = v1.w;
    }
    __syncthreads();
    int l = t >> 2, e2 = t & 3;
    int n = l & 15;
    unsigned* outp = (unsigned*)wcf;
#pragma unroll
    for (int c = 0; c < 4; ++c) {
        int d = c * 32 + (l >> 4) * 8 + e2 * 2;
        unsigned v = pk_bf16(Sw[d][n], Sw[d + 1][n]);
        outp[(size_t)((r * 100 + nt * 4 + c)) * 256 + t] = v;
    }
}

// ---------------------------------------------------------------------------
// Prep: gwbw[r] = sum_i g[i]*Wa[i][r];  gwbw[RR+r] = sum_i bb[i]*Wa[i][r].
// One block, 256 threads.
// ---------------------------------------------------------------------------
__global__ __launch_bounds__(256) void gwbw_kernel(
    const float* __restrict__ g, const float* __restrict__ bb,
    const float* __restrict__ Wa, float* __restrict__ gwbw)
{
    __shared__ float red[4][2 * RR];
    int t = threadIdx.x;
    float a1[RR], a2[RR];
#pragma unroll
    for (int r = 0; r < RR; ++r) { a1[r] = 0.f; a2[r] = 0.f; }
    for (int i = t; i < DIN; i += 256) {
        float gv = g[i], bv = bb[i];
#pragma unroll
        for (int r = 0; r < RR; ++r) {
            float wv = Wa[i * RR + r];
            a1[r] += gv * wv;
            a2[r] += bv * wv;
        }
    }
    for (int off = 32; off; off >>= 1) {
#pragma unroll
        for (int r = 0; r < RR; ++r) {
            a1[r] += __shfl_down(a1[r], off);
            a2[r] += __shfl_down(a2[r], off);
        }
    }
    int w = t >> 6, lane = t & 63;
    if (lane == 0) {
#pragma unroll
        for (int r = 0; r < RR; ++r) { red[w][r] = a1[r]; red[w][RR + r] = a2[r]; }
    }
    __syncthreads();
    if (t < 2 * RR)
        gwbw[t] = red[0][t] + red[1][t] + red[2][t] + red[3][t];
}

// ---------------------------------------------------------------------------
// Kernel 1 v2: act = clip(sigmoid(LN(z) @ W_act + b_act)); also emits zf.
// Single sweep: sum_i LN(z)_i*Wa_ir = rstd*ZGW[r] - rstd*m*gw[r] + bw[r].
// ---------------------------------------------------------------------------
__global__ __launch_bounds__(256) void act_kernel(
    const float* __restrict__ z, const float* __restrict__ g,
    const float* __restrict__ Wa, const float* __restrict__ ba,
    const float* __restrict__ gwbw,
    float* __restrict__ act_out, unsigned short* __restrict__ zf_out)
{
    int b = blockIdx.x;
    int t = threadIdx.x;
    __shared__ float zs[DIN];
    __shared__ float ws1[4], ws2[4];
    __shared__ float wr[4][RR];
    const float* zr = z + (size_t)b * DIN;
    float s = 0.f, s2 = 0.f;
    float zgw[RR];
#pragma unroll
    for (int r = 0; r < RR; ++r) zgw[r] = 0.f;
    for (int i = t; i < DIN; i += 256) {
        float v = zr[i]; zs[i] = v;
        s += v; s2 += v * v;
        float zg = v * g[i];
#pragma unroll
        for (int r = 0; r < RR; ++r) zgw[r] += zg * Wa[i * RR + r];
    }
    for (int off = 32; off; off >>= 1) {
        s += __shfl_down(s, off); s2 += __shfl_down(s2, off);
#pragma unroll
        for (int r = 0; r < RR; ++r) zgw[r] += __shfl_down(zgw[r], off);
    }
    int w = t >> 6, lane = t & 63;
    if (lane == 0) {
        ws1[w] = s; ws2[w] = s2;
#pragma unroll
        for (int r = 0; r < RR; ++r) wr[w][r] = zgw[r];
    }
    __syncthreads();
    // emit zf fragment (zs complete)
    if (zf_out) {
        int c = t >> 2, o = t & 3;
        const float* zp = zs + c * 32 + o * 8;
        unsigned d0 = pk_bf16(zp[0], zp[1]);
        unsigned d1 = pk_bf16(zp[2], zp[3]);
        unsigned d2 = pk_bf16(zp[4], zp[5]);
        unsigned d3 = pk_bf16(zp[6], zp[7]);
        size_t off2 = (((size_t)(b >> 4) * 64 + c) * 64 + (size_t)(o * 16 + (b & 15))) * 8;
        *(uint4*)(zf_out + off2) = make_uint4(d0, d1, d2, d3);
    }
    if (t < RR) {
        float ts  = ws1[0] + ws1[1] + ws1[2] + ws1[3];
        float ts2 = ws2[0] + ws2[1] + ws2[2] + ws2[3];
        float mean = ts * (1.0f / DIN);
        float var  = ts2 * (1.0f / DIN) - mean * mean;
        float rstd = rsqrtf(var + 1e-5f);
        float zg = wr[0][t] + wr[1][t] + wr[2][t] + wr[3][t];
        float v = rstd * zg - rstd * mean * gwbw[t] + gwbw[RR + t] + ba[t];
        float sg = 1.0f / (1.0f + expf(-v));
        sg = fminf(fmaxf(sg, 0.0f), 1.0f);
        act_out[(size_t)b * RR + t] = sg;
    }
}

// Two-pass fallback (mid/low tiers, no gwbw available).
__global__ __launch_bounds__(256) void act_kernel_fb(
    const float* __restrict__ z, const float* __restrict__ g, const float* __restrict__ bb,
    const float* __restrict__ Wa, const float* __restrict__ ba,
    float* __restrict__ act_out)
{
    int b = blockIdx.x;
    int t = threadIdx.x;
    __shared__ float zs[DIN];
    __shared__ float ws1[4], ws2[4];
    __shared__ float wr[4][RR];
    const float* zr = z + (size_t)b * DIN;
    float s = 0.f, s2 = 0.f;
    for (int i = t; i < DIN; i += 256) {
        float v = zr[i]; zs[i] = v; s += v; s2 += v * v;
    }
    for (int off = 32; off; off >>= 1) { s += __shfl_down(s, off); s2 += __shfl_down(s2, off); }
    int w = t >> 6, lane = t & 63;
    if (lane == 0) { ws1[w] = s; ws2[w] = s2; }
    __syncthreads();
    s  = ws1[0] + ws1[1] + ws1[2] + ws1[3];
    s2 = ws2[0] + ws2[1] + ws2[2] + ws2[3];
    float mean = s * (1.0f / DIN);
    float var  = s2 * (1.0f / DIN) - mean * mean;
    float rstd = rsqrtf(var + 1e-5f);
    float acc[RR];
#pragma unroll
    for (int r = 0; r < RR; ++r) acc[r] = 0.f;
    for (int i = t; i < DIN; i += 256) {
        float y = (zs[i] - mean) * rstd * g[i] + bb[i];
#pragma unroll
        for (int r = 0; r < RR; ++r) acc[r] += y * Wa[i * RR + r];
    }
    for (int off = 32; off; off >>= 1) {
#pragma unroll
        for (int r = 0; r < RR; ++r) acc[r] += __shfl_down(acc[r], off);
    }
    if (lane == 0) {
#pragma unroll
        for (int r = 0; r < RR; ++r) wr[w][r] = acc[r];
    }
    __syncthreads();
    if (t < RR) {
        float v = wr[0][t] + wr[1][t] + wr[2][t] + wr[3][t] + ba[t];
        float sg = 1.0f / (1.0f + expf(-v));
        sg = fminf(fmaxf(sg, 0.0f), 1.0f);
        act_out[(size_t)b * RR + t] = sg;
    }
}

// ---------------------------------------------------------------------------
// Kernel 2+3 FUSED (MFMA): pose = squash(zf @ wpf^T + bp);  u = pose_bf16 @ wc[r]
// ---------------------------------------------------------------------------
#define PV_STAGE(KS, AD, BD) do {                                                           \
    _Pragma("unroll")                                                                       \
    for (int q = 0; q < 4; ++q) {                                                           \
        int ch = w * 4 + q;                                                                 \
        int gi = ch >> 2, cc = ch & 3;                                                      \
        __builtin_amdgcn_global_load_lds(                                                   \
            (const __attribute__((address_space(1))) unsigned int*)(const void*)            \
                (zf + (((size_t)(zbase + gi) * 64) + (KS) * 4 + cc) * 512 + l * 8),         \
            (__attribute__((address_space(3))) unsigned int*)(void*)                        \
                ((AD) + ch * 512 + l * 8), 16, 0, 0);                                       \
        __builtin_amdgcn_global_load_lds(                                                   \
            (const __attribute__((address_space(1))) unsigned int*)(const void*)            \
                (wpf + (((size_t)(wbase + gi) * 64) + (KS) * 4 + cc) * 512 + l * 8),        \
            (__attribute__((address_space(3))) unsigned int*)(void*)                        \
                ((BD) + ch * 512 + l * 8), 16, 0, 0);                                       \
    }                                                                                       \
} while (0)

#define PV_COMPUTE(AD, BD) do {                                                             \
    _Pragma("unroll")                                                                       \
    for (int c = 0; c < 4; ++c) {                                                           \
        bf16x8 a[2], b[4];                                                                  \
        _Pragma("unroll")                                                                   \
        for (int i = 0; i < 2; ++i)                                                         \
            a[i] = *(const bf16x8*)((AD) + ((wrI * 2 + i) * 4 + c) * 512 + l * 8);          \
        _Pragma("unroll")                                                                   \
        for (int j = 0; j < 4; ++j)                                                         \
            b[j] = *(const bf16x8*)((BD) + ((wcI * 4 + j) * 4 + c) * 512 + l * 8);          \
        _Pragma("unroll")                                                                   \
        for (int i = 0; i < 2; ++i)                                                         \
            _Pragma("unroll")                                                               \
            for (int j = 0; j < 4; ++j)                                                     \
                acc[i][j] = __builtin_amdgcn_mfma_f32_16x16x32_bf16(a[i], b[j], acc[i][j], 0, 0, 0); \
    }                                                                                       \
} while (0)

__global__ __launch_bounds__(512) void pose_votes_mfma(
    const unsigned short* __restrict__ zf, const unsigned short* __restrict__ wpf,
    const unsigned short* __restrict__ wcf, const float* __restrict__ bp,
    float* __restrict__ pose_out, float* __restrict__ u_out)
{
    __shared__ __align__(16) char pool[135168];   // 132KB union
    __shared__ float sq[2][128];
    unsigned short* A0 = (unsigned short*)pool;
    unsigned short* A1 = (unsigned short*)(pool + 32768);
    unsigned short* B0 = (unsigned short*)(pool + 65536);
    unsigned short* B1 = (unsigned short*)(pool + 98304);
    unsigned short* AT = (unsigned short*)pool;
    unsigned short* BV = (unsigned short*)(pool + 32768);

    int m0 = blockIdx.x * 128, r = blockIdx.y;
    int t = threadIdx.x, w = t >> 6, l = t & 63;
    int wrI = w >> 1, wcI = w & 1;
    int lrow = l & 15, koff = l >> 4;
    int zbase = m0 >> 4;
    int wbase = r * 8;

    f32x4 acc[2][4];
#pragma unroll
    for (int i = 0; i < 2; ++i)
#pragma unroll
        for (int j = 0; j < 4; ++j) acc[i][j] = 0.0f;

    PV_STAGE(0, A0, B0);
    __syncthreads();
#pragma unroll 1
    for (int ks = 0; ks < 16; ks += 2) {
        if (ks + 1 < 16) PV_STAGE(ks + 1, A1, B1);
        PV_COMPUTE(A0, B0);
        __syncthreads();
        if (ks + 2 < 16) PV_STAGE(ks + 2, A0, B0);
        PV_COMPUTE(A1, B1);
        __syncthreads();
    }

    // ---- issue wcf DMA into BV ----
    const unsigned short* wrp = wcf + (size_t)r * 100 * 512;
#pragma unroll
    for (int q = 0; q < 13; ++q) {
        int chunk = w + q * 8;
        if (chunk < 100)
            __builtin_amdgcn_global_load_lds(
                (const __attribute__((address_space(1))) unsigned int*)(const void*)(wrp + (size_t)chunk * 512 + l * 8),
                (__attribute__((address_space(3))) unsigned int*)(void*)(BV + chunk * 512),
                16, 0, 0);
    }

    // ---- squash ----
    float bpv[4];
#pragma unroll
    for (int j = 0; j < 4; ++j) bpv[j] = bp[r * DP + wcI * 64 + j * 16 + lrow];
    float ns_[2][4];
#pragma unroll
    for (int i = 0; i < 2; ++i)
#pragma unroll
        for (int reg = 0; reg < 4; ++reg) {
            float ss = 0.f;
#pragma unroll
            for (int j = 0; j < 4; ++j) {
                float x = acc[i][j][reg] + bpv[j];
                acc[i][j][reg] = x;
                ss += x * x;
            }
            ss += __shfl_xor(ss, 1); ss += __shfl_xor(ss, 2);
            ss += __shfl_xor(ss, 4); ss += __shfl_xor(ss, 8);
            ns_[i][reg] = ss;
        }
    if (lrow == 0) {
#pragma unroll
        for (int i = 0; i < 2; ++i)
#pragma unroll
            for (int reg = 0; reg < 4; ++reg)
                sq[wcI][wrI * 32 + i * 16 + koff * 4 + reg] = ns_[i][reg];
    }
    __syncthreads();

#pragma unroll
    for (int i = 0; i < 2; ++i)
#pragma unroll
        for (int reg = 0; reg < 4; ++reg) {
            int rl = wrI * 32 + i * 16 + koff * 4 + reg;
            float ns = sq[0][rl] + sq[1][rl];
            float factor = (ns / fmaxf(1.0f + ns, 1e-6f)) / (sqrtf(ns) + 1e-6f);
            size_t rowbase = ((size_t)(m0 + rl) * RR + r) * DP;
            int g8 = rl >> 4, r15 = rl & 15;
#pragma unroll
            for (int j = 0; j < 4; ++j) {
                float v = acc[i][j][reg] * factor;
                int col = wcI * 64 + j * 16 + lrow;
                pose_out[rowbase + col] = v;
                int cseg = col >> 5;
                int l2 = r15 + 16 * ((col >> 3) & 3);
                AT[(size_t)((g8 * 4 + cseg) * 64 + l2) * 8 + (col & 7)] = bf16_1(v);
            }
        }
    __syncthreads();

    bf16x8 af2[4];
#pragma unroll
    for (int c = 0; c < 4; ++c)
        af2[c] = *(const bf16x8*)(AT + (size_t)((w * 4 + c) * 64 + l) * 8);
    int crow = (l >> 4) * 4;
#pragma unroll 1
    for (int nt = 0; nt < 25; ++nt) {
        f32x4 a2 = 0.0f;
#pragma unroll
        for (int c = 0; c < 4; ++c) {
            bf16x8 bfr = *(const bf16x8*)(BV + (size_t)((nt * 4 + c) * 64 + l) * 8);
            a2 = __builtin_amdgcn_mfma_f32_16x16x32_bf16(af2[c], bfr, a2, 0, 0, 0);
        }
#pragma unroll
        for (int reg = 0; reg < 4; ++reg) {
            int row = m0 + w * 16 + crow + reg;
            u_out[((size_t)row * RR + r) * KH + nt * 16 + (l & 15)] = a2[reg];
        }
    }
}

// ---------------------------------------------------------------------------
// Kernel 2 v1 (MFMA) — mid-tier fallback.
// ---------------------------------------------------------------------------
__global__ __launch_bounds__(256) void pose_mfma(
    const float* __restrict__ z, const unsigned short* __restrict__ WpT,
    const float* __restrict__ bp, float* __restrict__ pose_out)
{
    __shared__ __align__(16) unsigned short As[128 * 40];
    __shared__ __align__(16) unsigned short Bs[128 * 40];
    __shared__ float sq[2][128];
    int m0 = blockIdx.x * 128, r = blockIdx.y, t = threadIdx.x;
    int n0 = r * DP;
    int w = t >> 6, l = t & 63;
    int lrow = l & 15, koff = l >> 4;
    int rbase = (w >> 1) * 64, cbase = (w & 1) * 64;
    f32x4 acc[4][4];
#pragma unroll
    for (int i = 0; i < 4; ++i)
#pragma unroll
        for (int j = 0; j < 4; ++j) acc[i][j] = 0.0f;
    for (int kt = 0; kt < DIN; kt += 32) {
#pragma unroll
        for (int q = 0; q < 4; ++q) {
            int s = t + 256 * q;
            int row = s >> 3, k4 = s & 7;
            float4 v = *(const float4*)(z + (size_t)(m0 + row) * DIN + kt + k4 * 4);
            *(uint2*)(As + row * 40 + k4 * 4) = make_uint2(pk_bf16(v.x, v.y), pk_bf16(v.z, v.w));
        }
#pragma unroll
        for (int q = 0; q < 2; ++q) {
            int s = t + 256 * q;
            int col = s >> 2, k8 = s & 3;
            uint4 v = *(const uint4*)(WpT + (size_t)(n0 + col) * DIN + kt + k8 * 8);
            *(uint4*)(Bs + col * 40 + k8 * 8) = v;
        }
        __syncthreads();
        bf16x8 a[4], b[4];
#pragma unroll
        for (int i = 0; i < 4; ++i)
            a[i] = *(const bf16x8*)(As + (rbase + i * 16 + lrow) * 40 + koff * 8);
#pragma unroll
        for (int j = 0; j < 4; ++j)
            b[j] = *(const bf16x8*)(Bs + (cbase + j * 16 + lrow) * 40 + koff * 8);
#pragma unroll
        for (int i = 0; i < 4; ++i)
#pragma unroll
            for (int j = 0; j < 4; ++j)
                acc[i][j] = __builtin_amdgcn_mfma_f32_16x16x32_bf16(a[i], b[j], acc[i][j], 0, 0, 0);
        __syncthreads();
    }
    float bpv[4];
#pragma unroll
    for (int j = 0; j < 4; ++j) bpv[j] = bp[n0 + cbase + j * 16 + lrow];
    float ns_[4][4];
#pragma unroll
    for (int i = 0; i < 4; ++i)
#pragma unroll
        for (int reg = 0; reg < 4; ++reg) {
            float ss = 0.f;
#pragma unroll
            for (int j = 0; j < 4; ++j) {
                float x = acc[i][j][reg] + bpv[j];
                acc[i][j][reg] = x;
                ss += x * x;
            }
            ss += __shfl_xor(ss, 1); ss += __shfl_xor(ss, 2);
            ss += __shfl_xor(ss, 4); ss += __shfl_xor(ss, 8);
            ns_[i][reg] = ss;
        }
    if (lrow == 0) {
#pragma unroll
        for (int i = 0; i < 4; ++i)
#pragma unroll
            for (int reg = 0; reg < 4; ++reg)
                sq[w & 1][rbase + i * 16 + koff * 4 + reg] = ns_[i][reg];
    }
    __syncthreads();
#pragma unroll
    for (int i = 0; i < 4; ++i)
#pragma unroll
        for (int reg = 0; reg < 4; ++reg) {
            int rl = rbase + i * 16 + koff * 4 + reg;
            float ns = sq[0][rl] + sq[1][rl];
            float factor = (ns / fmaxf(1.0f + ns, 1e-6f)) / (sqrtf(ns) + 1e-6f);
            size_t rowbase = ((size_t)(m0 + rl) * RR + r) * DP;
#pragma unroll
            for (int j = 0; j < 4; ++j)
                pose_out[rowbase + cbase + j * 16 + lrow] = acc[i][j][reg] * factor;
        }
}

// ---------------------------------------------------------------------------
// Kernel 3 (MFMA) — mid-tier fallback.
// ---------------------------------------------------------------------------
__global__ __launch_bounds__(256) void votes_mfma(
    const float* __restrict__ pose, const unsigned short* __restrict__ wcT,
    float* __restrict__ u_out)
{
    __shared__ __align__(16) unsigned short As[128 * 152];
    __shared__ __align__(16) unsigned short Bs[80 * 152];
    int m0 = blockIdx.x * 128, r = blockIdx.y, n0 = blockIdx.z * 80;
    int t = threadIdx.x;
    int w = t >> 6, l = t & 63;
    int lrow = l & 15, koff = l >> 4;
    int rbase = w * 32;
#pragma unroll
    for (int q = 0; q < 16; ++q) {
        int s = t + 256 * q;
        int row = s >> 5, k4 = s & 31;
        float4 v = *(const float4*)(pose + ((size_t)(m0 + row) * RR + r) * DP + k4 * 4);
        *(uint2*)(As + row * 152 + k4 * 4) = make_uint2(pk_bf16(v.x, v.y), pk_bf16(v.z, v.w));
    }
    const unsigned short* wr_ = wcT + (size_t)r * KH * DP;
#pragma unroll
    for (int q = 0; q < 5; ++q) {
        int s = t + 256 * q;
        int col = s >> 4, k8 = s & 15;
        uint4 v = *(const uint4*)(wr_ + (size_t)(n0 + col) * DP + k8 * 8);
        *(uint4*)(Bs + col * 152 + k8 * 8) = v;
    }
    __syncthreads();
    f32x4 acc[2][5];
#pragma unroll
    for (int i = 0; i < 2; ++i)
#pragma unroll
        for (int j = 0; j < 5; ++j) acc[i][j] = 0.0f;
#pragma unroll
    for (int ks = 0; ks < 4; ++ks) {
        bf16x8 a[2], b[5];
#pragma unroll
        for (int i = 0; i < 2; ++i)
            a[i] = *(const bf16x8*)(As + (rbase + i * 16 + lrow) * 152 + ks * 32 + koff * 8);
#pragma unroll
        for (int j = 0; j < 5; ++j)
            b[j] = *(const bf16x8*)(Bs + (j * 16 + lrow) * 152 + ks * 32 + koff * 8);
#pragma unroll
        for (int i = 0; i < 2; ++i)
#pragma unroll
            for (int j = 0; j < 5; ++j)
                acc[i][j] = __builtin_amdgcn_mfma_f32_16x16x32_bf16(a[i], b[j], acc[i][j], 0, 0, 0);
    }
#pragma unroll
    for (int i = 0; i < 2; ++i)
#pragma unroll
        for (int reg = 0; reg < 4; ++reg) {
            int row = m0 + rbase + i * 16 + koff * 4 + reg;
            size_t base = ((size_t)row * RR + r) * KH + n0;
#pragma unroll
            for (int j = 0; j < 5; ++j)
                u_out[base + j * 16 + lrow] = acc[i][j][reg];
        }
}

// ---------------------------------------------------------------------------
// Kernel 4 v2: routing — one wave per batch row; fully wave-parallel phases.
// ---------------------------------------------------------------------------
__global__ __launch_bounds__(64) void routing_kernel(
    const float* __restrict__ u_in, const float* __restrict__ act_in,
    const float* __restrict__ lncg, const float* __restrict__ lncb,
    const float* __restrict__ beta_u,
    float* __restrict__ q_out, float* __restrict__ cp_out,
    float* __restrict__ ca_out, float* __restrict__ rce_out,
    float* __restrict__ ce_out)
{
    __shared__ __align__(16) float U[RKH];
    __shared__ float Q[RK];
    __shared__ float CP[KH];
    __shared__ float AG[RK];      // doubles as WT (= Q*A7) before each CP phase
    __shared__ float A7[RR];
    int b = blockIdx.x, t = threadIdx.x;
    const float4* u4 = (const float4*)(u_in + (size_t)b * RKH);
    float4* U4 = (float4*)U;
    for (int p = t; p < RKH / 4; p += 64) U4[p] = u4[p];
    if (t < RR) A7[t] = act_in[(size_t)b * RR + t];
    for (int p = t; p < RK; p += 64) Q[p] = 1.0f / KK;
    int kg = t >> 4, hl = t & 15;              // LN grouping: 4 groups x 16 lanes
    float lg = lncg[hl], lb = lncb[hl];
    int rg = t >> 3, li = t & 7;               // softmax grouping: 8 groups x 8 lanes
    __syncthreads();
    for (int it = 0; it < NITERS; ++it) {
        // WT[p] = Q[p] * A7[r]
        for (int p = t; p < RK; p += 64) AG[p] = Q[p] * A7[p / KK];
        __syncthreads();
        // CP[p] = sum_r WT[r*KK+k] * U[r*KH+p]
        for (int p = t; p < KH; p += 64) {
            int k = p >> 4;
            float s = 0.f;
#pragma unroll
            for (int r = 0; r < RR; ++r) s += AG[r * KK + k] * U[r * KH + p];
            CP[p] = s;
        }
        __syncthreads();
        // LN over each k-row of DC=16; 4 k-rows in parallel, 7 passes
#pragma unroll
        for (int pass = 0; pass < 7; ++pass) {
            int k = kg + 4 * pass;
            bool ok = k < KK;
            float v = ok ? CP[k * DC + hl] : 0.f;
            float s1 = v, s2v = v * v;
            s1 += __shfl_xor(s1, 1); s2v += __shfl_xor(s2v, 1);
            s1 += __shfl_xor(s1, 2); s2v += __shfl_xor(s2v, 2);
            s1 += __shfl_xor(s1, 4); s2v += __shfl_xor(s2v, 4);
            s1 += __shfl_xor(s1, 8); s2v += __shfl_xor(s2v, 8);
            float mean = s1 * (1.0f / DC);
            float var  = s2v * (1.0f / DC) - mean * mean;
            float rstd = rsqrtf(var + 1e-5f);
            if (ok) CP[k * DC + hl] = (v - mean) * rstd * lg + lb;
        }
        __syncthreads();
        // AG[p] = 0.25 * sum_h CP[k*DC+h] * U[r*KH + k*DC + h]
        for (int p = t; p < RK; p += 64) {
            int r = p / KK, k = p - r * KK;
            float s = 0.f;
#pragma unroll
            for (int h = 0; h < DC; ++h) s += CP[k * DC + h] * U[r * KH + k * DC + h];
            AG[p] = s * 0.25f;
        }
        __syncthreads();
        // softmax over k per r: group of 8 lanes per r, 4 k-slots/lane
        {
            float av[4];
            float mx = -1e30f;
#pragma unroll
            for (int j2 = 0; j2 < 4; ++j2) {
                int k = li + 8 * j2;
                av[j2] = (rg < RR && k < KK) ? AG[rg * KK + k] : -1e30f;
                mx = fmaxf(mx, av[j2]);
            }
            mx = fmaxf(mx, __shfl_xor(mx, 1));
            mx = fmaxf(mx, __shfl_xor(mx, 2));
            mx = fmaxf(mx, __shfl_xor(mx, 4));
            float sum = 0.f;
#pragma unroll
            for (int j2 = 0; j2 < 4; ++j2) {
                av[j2] = __expf(av[j2] - mx);
                sum += av[j2];
            }
            sum += __shfl_xor(sum, 1); sum += __shfl_xor(sum, 2); sum += __shfl_xor(sum, 4);
            float inv = 1.0f / sum;
#pragma unroll
            for (int j2 = 0; j2 < 4; ++j2) {
                int k = li + 8 * j2;
                if (rg < RR && k < KK) Q[rg * KK + k] = av[j2] * inv;
            }
        }
        __syncthreads();
    }
    if (t < KK) {
        float s = 0.f;
#pragma unroll
        for (int r = 0; r < RR; ++r) s += Q[r * KK + t] * A7[r];
        ca_out[(size_t)b * KK + t] = 1.0f / (1.0f + expf(-(beta_u[t] + s)));
    }
    for (int p = t; p < RK; p += 64) q_out[(size_t)b * RK + p] = Q[p];
    for (int p = t; p < KH; p += 64) cp_out[(size_t)b * KH + p] = CP[p];
    float4* rce4 = (float4*)(rce_out + (size_t)b * RKH);
    float4* ce4  = (float4*)ce_out;
    for (int p4 = t; p4 < RKH / 4; p4 += 64) {
        int base = p4 * 4;
        int r  = base / KH;
        int k  = (base % KH) / DC;
        int h0 = base % DC;
        float qv = Q[r * KK + k];
        float4 uv = U4[p4];
        float4 rv = make_float4(qv * uv.x, qv * uv.y, qv * uv.z, qv * uv.w);
        rce4[p4] = rv;
        size_t ci = ((size_t)b * RKH + (size_t)k * HD + (size_t)r * DC + h0) >> 2;
        ce4[ci] = rv;
    }
}

// ---------------------------------------------------------------------------
// Kernel 5 (MFMA): head — persistent blocks, 512 threads.
// ---------------------------------------------------------------------------
__global__ __launch_bounds__(512) void head_mfma(
    const float* __restrict__ ce, const float* __restrict__ g, const float* __restrict__ bb,
    const unsigned short* __restrict__ W1F, const float* __restrict__ b1,
    const float* __restrict__ W2, const float* __restrict__ b2,
    float* __restrict__ logits)
{
    __shared__ __align__(16) unsigned short As[128 * 128];
    __shared__ __align__(16) unsigned short Bs[448 * 128];
    __shared__ float LB1[H4];
    __shared__ float LW2[H4];
    int t = threadIdx.x;
    int w = t >> 6, l = t & 63;
    int lrow = l & 15, koff = l >> 4;

#pragma unroll
    for (int q = 0; q < 14; ++q) {
        int chunk = w * 14 + q;
        __builtin_amdgcn_global_load_lds(
            (const __attribute__((address_space(1))) unsigned int*)(const void*)(W1F + (size_t)chunk * 512 + l * 8),
            (__attribute__((address_space(3))) unsigned int*)(void*)(Bs + chunk * 512),
            16, 0, 0);
    }
    if (t >= 256) {
        for (int s = t - 256; s < H4; s += 256) { LB1[s] = b1[s]; LW2[s] = W2[s]; }
    }
    float b2v = b2[0];

    int row = t >> 1, half = t & 1;
    int lr = row & 15, rt = row >> 4;

    float4 v[14];
    int tile = blockIdx.x;
    if (t < 256 && tile < HEAD_TILES) {
        const float* rp = ce + (size_t)(tile * 128 + row) * HD + half * 56;
#pragma unroll
        for (int m = 0; m < 14; ++m) v[m] = *(const float4*)(rp + m * 4);
    }

    bool first = true;
    for (; tile < HEAD_TILES; tile += 256) {
        if (!first) __syncthreads();
        first = false;

        if (t < 256) {
            float s1 = 0.f, s2 = 0.f;
#pragma unroll
            for (int m = 0; m < 14; ++m) {
                s1 += v[m].x + v[m].y + v[m].z + v[m].w;
                s2 += v[m].x * v[m].x + v[m].y * v[m].y + v[m].z * v[m].z + v[m].w * v[m].w;
            }
            s1 += __shfl_xor(s1, 1); s2 += __shfl_xor(s2, 1);
            float mean = s1 * (1.0f / HD);
            float var  = s2 * (1.0f / HD) - mean * mean;
            float rstd = rsqrtf(var + 1e-5f);
#pragma unroll
            for (int j = 0; j < 7; ++j) {
                float4 gl0 = *(const float4*)(g  + half * 56 + j * 8);
                float4 gl1 = *(const float4*)(g  + half * 56 + j * 8 + 4);
                float4 bl0 = *(const float4*)(bb + half * 56 + j * 8);
                float4 bl1 = *(const float4*)(bb + half * 56 + j * 8 + 4);
                float4 x0 = v[j * 2], x1 = v[j * 2 + 1];
                float y0 = (x0.x - mean) * rstd * gl0.x + bl0.x;
                float y1 = (x0.y - mean) * rstd * gl0.y + bl0.y;
                float y2 = (x0.z - mean) * rstd * gl0.z + bl0.z;
                float y3 = (x0.w - mean) * rstd * gl0.w + bl0.w;
                float y4 = (x1.x - mean) * rstd * gl1.x + bl1.x;
                float y5 = (x1.y - mean) * rstd * gl1.y + bl1.y;
                float y6 = (x1.z - mean) * rstd * gl1.z + bl1.z;
                float y7 = (x1.w - mean) * rstd * gl1.w + bl1.w;
                int k8 = half * 7 + j;
                int ks = k8 >> 2, ko = k8 & 3;
                unsigned* dst = (unsigned*)(As + (size_t)((rt * 4 + ks) * 64 + ko * 16 + lr) * 8);
                dst[0] = pk_bf16(y0, y1); dst[1] = pk_bf16(y2, y3);
                dst[2] = pk_bf16(y4, y5); dst[3] = pk_bf16(y6, y7);
            }
            if (half) {
                uint4 z4 = make_uint4(0, 0, 0, 0);
                *(uint4*)(As + (size_t)((rt * 4 + 3) * 64 + 2 * 16 + lr) * 8) = z4;
                *(uint4*)(As + (size_t)((rt * 4 + 3) * 64 + 3 * 16 + lr) * 8) = z4;
            }
        }
        __syncthreads();

        bf16x8 af[4];
#pragma unroll
        for (int ks = 0; ks < 4; ++ks)
            af[ks] = *(const bf16x8*)(As + (size_t)((w * 4 + ks) * 64 + l) * 8);

        if (t < 256 && tile + 256 < HEAD_TILES) {
            const float* rp = ce + (size_t)((tile + 256) * 128 + row) * HD + half * 56;
#pragma unroll
            for (int m = 0; m < 14; ++m) v[m] = *(const float4*)(rp + m * 4);
        }

        float logitAcc[4];
#pragma unroll
        for (int reg = 0; reg < 4; ++reg) logitAcc[reg] = 0.f;

        for (int nc = 0; nc < 7; ++nc) {
            float b1v[4], w2v[4];
#pragma unroll
            for (int j = 0; j < 4; ++j) {
                b1v[j] = LB1[nc * 64 + j * 16 + lrow];
                w2v[j] = LW2[nc * 64 + j * 16 + lrow];
            }
            f32x4 acc[4];
#pragma unroll
            for (int j = 0; j < 4; ++j) acc[j] = 0.0f;
#pragma unroll
            for (int ks = 0; ks < 4; ++ks) {
                bf16x8 bfr[4];
#pragma unroll
                for (int j = 0; j < 4; ++j)
                    bfr[j] = *(const bf16x8*)(Bs + (size_t)(((nc * 4 + ks) * 4 + j) * 64 + l) * 8);
#pragma unroll
                for (int j = 0; j < 4; ++j)
                    acc[j] = __builtin_amdgcn_mfma_f32_16x16x32_bf16(af[ks], bfr[j], acc[j], 0, 0, 0);
            }
#pragma unroll
            for (int reg = 0; reg < 4; ++reg) {
                float sum = 0.f;
#pragma unroll
                for (int j = 0; j < 4; ++j) {
                    float x = acc[j][reg] + b1v[j];
                    sum += gelu_fast(x) * w2v[j];
                }
                logitAcc[reg] += sum;
            }
        }
#pragma unroll
        for (int reg = 0; reg < 4; ++reg) {
            float vv = logitAcc[reg];
            vv += __shfl_xor(vv, 1); vv += __shfl_xor(vv, 2);
            vv += __shfl_xor(vv, 4); vv += __shfl_xor(vv, 8);
            if (lrow == 0)
                logits[(size_t)tile * 128 + w * 16 + koff * 4 + reg] = vv + b2v;
        }
    }
}

// ===========================================================================
// Fallback fp32 kernels (lowest tier).
// ===========================================================================
__global__ __launch_bounds__(256) void pose_kernel(
    const float* __restrict__ z, const float* __restrict__ Wp, const float* __restrict__ bp,
    float* __restrict__ pose_out)
{
    __shared__ __align__(16) float As[64 * 36];
    __shared__ __align__(16) float Bs[32 * 128];
    int m0 = blockIdx.x * 64;
    int r  = blockIdx.y;
    int n0 = r * DP;
    int t  = threadIdx.x;
    int rg = t >> 5;
    int cg = t & 31;
    float acc[8][4] = {};
    for (int kt = 0; kt < DIN; kt += 32) {
#pragma unroll
        for (int q = 0; q < 2; ++q) {
            int s = t * 2 + q;
            int row = s >> 3, k4 = s & 7;
            float4 v = *(const float4*)(z + (size_t)(m0 + row) * DIN + kt + k4 * 4);
            *(float4*)(As + row * 36 + k4 * 4) = v;
        }
#pragma unroll
        for (int q = 0; q < 4; ++q) {
            int s = t + 256 * q;
            int row = s >> 5, c4 = s & 31;
            float4 v = *(const float4*)(Wp + (size_t)(kt + row) * (RR * DP) + n0 + c4 * 4);
            *(float4*)(Bs + row * 128 + c4 * 4) = v;
        }
        __syncthreads();
#pragma unroll
        for (int kk = 0; kk < 32; ++kk) {
            float4 bv = *(const float4*)(Bs + kk * 128 + cg * 4);
#pragma unroll
            for (int j = 0; j < 8; ++j) {
                float a = As[(rg * 8 + j) * 36 + kk];
                acc[j][0] += a * bv.x; acc[j][1] += a * bv.y;
                acc[j][2] += a * bv.z; acc[j][3] += a * bv.w;
            }
        }
        __syncthreads();
    }
    float bi0 = bp[n0 + cg * 4], bi1 = bp[n0 + cg * 4 + 1];
    float bi2 = bp[n0 + cg * 4 + 2], bi3 = bp[n0 + cg * 4 + 3];
#pragma unroll
    for (int j = 0; j < 8; ++j) {
        float x0 = acc[j][0] + bi0, x1 = acc[j][1] + bi1;
        float x2 = acc[j][2] + bi2, x3 = acc[j][3] + bi3;
        float ns = x0 * x0 + x1 * x1 + x2 * x2 + x3 * x3;
        for (int off = 1; off < 32; off <<= 1) ns += __shfl_xor(ns, off);
        float factor = (ns / fmaxf(1.0f + ns, 1e-6f)) / (sqrtf(ns) + 1e-6f);
        int row = m0 + rg * 8 + j;
        float4 o = make_float4(x0 * factor, x1 * factor, x2 * factor, x3 * factor);
        *(float4*)(pose_out + ((size_t)row * RR + r) * DP + cg * 4) = o;
    }
}

__global__ __launch_bounds__(256) void votes_kernel(
    const float* __restrict__ pose, const float* __restrict__ wc,
    float* __restrict__ u_out)
{
    __shared__ float As[64 * 129];
    __shared__ __align__(16) float Bs[64 * 80];
    int m0 = blockIdx.x * 64;
    int r  = blockIdx.y;
    int n0 = blockIdx.z * 80;
    int t  = threadIdx.x;
    const size_t wbase = (size_t)r * DP * KH;
#pragma unroll
    for (int q = 0; q < 8; ++q) {
        int s = t + 256 * q;
        int row = s >> 5, d4 = s & 31;
        float4 v = *(const float4*)(pose + ((size_t)(m0 + row) * RR + r) * DP + d4 * 4);
        As[row * 129 + d4 * 4 + 0] = v.x;
        As[row * 129 + d4 * 4 + 1] = v.y;
        As[row * 129 + d4 * 4 + 2] = v.z;
        As[row * 129 + d4 * 4 + 3] = v.w;
    }
    int m4 = t >> 4, n5 = t & 15;
    float acc[4][5];
#pragma unroll
    for (int i = 0; i < 4; ++i)
#pragma unroll
        for (int j = 0; j < 5; ++j) acc[i][j] = 0.f;
    for (int kt = 0; kt < DP; kt += 64) {
        __syncthreads();
#pragma unroll
        for (int q = 0; q < 5; ++q) {
            int s = t + 256 * q;
            int d = s / 20, c4 = s % 20;
            float4 v = *(const float4*)(wc + wbase + (size_t)(kt + d) * KH + n0 + c4 * 4);
            *(float4*)(Bs + d * 80 + c4 * 4) = v;
        }
        __syncthreads();
#pragma unroll 4
        for (int dd = 0; dd < 64; ++dd) {
            int d = kt + dd;
            float b_[5];
#pragma unroll
            for (int j = 0; j < 5; ++j) b_[j] = Bs[dd * 80 + n5 * 5 + j];
#pragma unroll
            for (int i = 0; i < 4; ++i) {
                float a = As[(m4 * 4 + i) * 129 + d];
#pragma unroll
                for (int j = 0; j < 5; ++j) acc[i][j] += a * b_[j];
            }
        }
    }
#pragma unroll
    for (int i = 0; i < 4; ++i) {
        int row = m0 + m4 * 4 + i;
        size_t base = ((size_t)row * RR + r) * KH + n0 + n5 * 5;
#pragma unroll
        for (int j = 0; j < 5; ++j) u_out[base + j] = acc[i][j];
    }
}

__global__ __launch_bounds__(256) void head_kernel(
    const float* __restrict__ ce, const float* __restrict__ g, const float* __restrict__ bb,
    const float* __restrict__ W1, const float* __restrict__ b1,
    const float* __restrict__ W2, const float* __restrict__ b2,
    float* __restrict__ logits)
{
    __shared__ __align__(16) float Y[64 * HD];
    __shared__ float Wc[HD * 64];
    __shared__ float Lg[64];
    int row0 = blockIdx.x * 64;
    int t = threadIdx.x;
    for (int s = t; s < 64 * HD; s += 256) Y[s] = ce[(size_t)row0 * HD + s];
    __syncthreads();
    if (t < 64) {
        float m = 0.f;
        for (int i = 0; i < HD; ++i) m += Y[t * HD + i];
        m *= (1.0f / HD);
        float v = 0.f;
        for (int i = 0; i < HD; ++i) { float d = Y[t * HD + i] - m; v += d * d; }
        v *= (1.0f / HD);
        float rstd = rsqrtf(v + 1e-5f);
        for (int i = 0; i < HD; ++i) Y[t * HD + i] = (Y[t * HD + i] - m) * rstd * g[i] + bb[i];
    }
    int rg = t >> 4;
    int cg = t & 15;
    float accRow[4] = {0.f, 0.f, 0.f, 0.f};
    for (int c0 = 0; c0 < H4; c0 += 64) {
        __syncthreads();
        for (int s = t; s < HD * 64; s += 256) {
            int i = s >> 6, c = s & 63;
            Wc[i * 64 + c] = W1[(size_t)i * H4 + c0 + c];
        }
        __syncthreads();
        float b1v[4], w2v[4];
#pragma unroll
        for (int c = 0; c < 4; ++c) { b1v[c] = b1[c0 + cg * 4 + c]; w2v[c] = W2[c0 + cg * 4 + c]; }
        float s_[4][4];
#pragma unroll
        for (int rr = 0; rr < 4; ++rr)
#pragma unroll
            for (int c = 0; c < 4; ++c) s_[rr][c] = b1v[c];
        for (int i4 = 0; i4 < HD / 4; ++i4) {
            float4 y4[4];
#pragma unroll
            for (int rr = 0; rr < 4; ++rr)
                y4[rr] = *(const float4*)(Y + (rg * 4 + rr) * HD + i4 * 4);
#pragma unroll
            for (int is = 0; is < 4; ++is) {
                float w_[4];
#pragma unroll
                for (int c = 0; c < 4; ++c) w_[c] = Wc[(i4 * 4 + is) * 64 + cg * 4 + c];
#pragma unroll
                for (int rr = 0; rr < 4; ++rr) {
                    float yv = (is == 0) ? y4[rr].x : (is == 1) ? y4[rr].y : (is == 2) ? y4[rr].z : y4[rr].w;
#pragma unroll
                    for (int c = 0; c < 4; ++c) s_[rr][c] += yv * w_[c];
                }
            }
        }
#pragma unroll
        for (int rr = 0; rr < 4; ++rr) {
#pragma unroll
            for (int c = 0; c < 4; ++c) {
                float x = s_[rr][c];
                float ge = 0.5f * x * (1.0f + erff(x * 0.70710678118654752440f));
                accRow[rr] += ge * w2v[c];
            }
        }
    }
#pragma unroll
    for (int rr = 0; rr < 4; ++rr) {
        float v = accRow[rr];
        v += __shfl_xor(v, 1); v += __shfl_xor(v, 2);
        v += __shfl_xor(v, 4); v += __shfl_xor(v, 8);
        if (cg == 0) Lg[rg * 4 + rr] = v;
    }
    __syncthreads();
    if (t < 64) logits[row0 + t] = Lg[t] + b2[0];
}

// ---------------------------------------------------------------------------
extern "C" void kernel_launch(void* const* d_in, const int* in_sizes, int n_in,
                              void* d_out, int out_size, void* d_ws, size_t ws_size,
                              hipStream_t stream) {
    const float* z    = (const float*)d_in[0];
    const float* Wp   = (const float*)d_in[1];
    const float* bp   = (const float*)d_in[2];
    const float* lnag = (const float*)d_in[3];
    const float* lnab = (const float*)d_in[4];
    const float* Wa   = (const float*)d_in[5];
    const float* ba   = (const float*)d_in[6];
    const float* wc   = (const float*)d_in[7];
    const float* lncg = (const float*)d_in[8];
    const float* lncb = (const float*)d_in[9];
    const float* beta = (const float*)d_in[10];
    const float* lnhg = (const float*)d_in[11];
    const float* lnhb = (const float*)d_in[12];
    const float* W1   = (const float*)d_in[13];
    const float* b1   = (const float*)d_in[14];
    const float* W2   = (const float*)d_in[15];
    const float* b2   = (const float*)d_in[16];

    float* out = (float*)d_out;
    float* o_logits = out;
    float* o_ce   = o_logits + (size_t)BB * KK;
    float* o_cp   = o_ce   + (size_t)BB * KK * HD;
    float* o_ca   = o_cp   + (size_t)BB * KK * DC;
    float* o_q    = o_ca   + (size_t)BB * KK;
    float* o_pose = o_q    + (size_t)BB * RK;
    float* o_act  = o_pose + (size_t)BB * RR * DP;
    float* o_rce  = o_act  + (size_t)BB * RR;

    // workspace layout: [W1F | wcf/wcT | zf | wpf | gwbw(16 f32)]
    const size_t W1F_ELE = (size_t)H4 * 128;              // 57344
    const size_t WCF_ELE = (size_t)RR * 100 * 512;        // 358400
    const size_t ZF_ELE  = (size_t)BB * DIN;              // 8388608
    const size_t WPF_ELE = (size_t)(RR * DP) * DIN;       // 1835008
    const size_t GW_ELE  = 32;                            // 16 floats as shorts
    unsigned short* W1F = (unsigned short*)d_ws;
    unsigned short* wcf = W1F + W1F_ELE;
    unsigned short* zf  = wcf + WCF_ELE;
    unsigned short* wpf = zf + ZF_ELE;
    float*          gwbw = (float*)(wpf + WPF_ELE);
    unsigned short* wcT = wcf;   // mid-tier alias
    unsigned short* WpT = zf;    // mid-tier alias

    const size_t WS_NEW = (W1F_ELE + WCF_ELE + ZF_ELE + WPF_ELE + GW_ELE) * sizeof(unsigned short);
    const size_t WS_MID = (W1F_ELE + WCF_ELE + WPF_ELE) * sizeof(unsigned short);

    if (ws_size >= WS_NEW) {
        hipLaunchKernelGGL(gwbw_kernel, dim3(1), dim3(256), 0, stream, lnag, lnab, Wa, gwbw);
        hipLaunchKernelGGL(act_kernel, dim3(BB), dim3(256), 0, stream,
                           z, lnag, Wa, ba, gwbw, o_act, zf);
        hipLaunchKernelGGL(wpf_kernel, dim3(896), dim3(256), 0, stream, Wp, wpf);
        hipLaunchKernelGGL(w1_frag_kernel, dim3(112), dim3(256), 0, stream, W1, W1F);
        hipLaunchKernelGGL(wcf_kernel, dim3(RR, 25), dim3(256), 0, stream, wc, wcf);
        hipLaunchKernelGGL(pose_votes_mfma, dim3(BB / 128, RR), dim3(512), 0, stream,
                           zf, wpf, wcf, bp, o_pose, o_rce);
        hipLaunchKernelGGL(routing_kernel, dim3(BB), dim3(64), 0, stream,
                           o_rce, o_act, lncg, lncb, beta, o_q, o_cp, o_ca, o_rce, o_ce);
        hipLaunchKernelGGL(head_mfma, dim3(256), dim3(512), 0, stream,
                           o_ce, lnhg, lnhb, W1F, b1, W2, b2, o_logits);
    } else if (ws_size >= WS_MID) {
        hipLaunchKernelGGL(act_kernel_fb, dim3(BB), dim3(256), 0, stream,
                           z, lnag, lnab, Wa, ba, o_act);
        hipLaunchKernelGGL(transpose_cvt_kernel, dim3(DIN / 64, (RR * DP) / 64, 1), dim3(256), 0, stream,
                           Wp, WpT, DIN, RR * DP);
        hipLaunchKernelGGL(w1_frag_kernel, dim3(112), dim3(256), 0, stream, W1, W1F);
        hipLaunchKernelGGL(transpose_cvt_kernel, dim3(2, 7, RR), dim3(256), 0, stream,
                           wc, wcT, DP, KH);
        hipLaunchKernelGGL(pose_mfma, dim3(BB / 128, RR), dim3(256), 0, stream,
                           z, WpT, bp, o_pose);
        hipLaunchKernelGGL(votes_mfma, dim3(BB / 128, RR, 5), dim3(256), 0, stream,
                           o_pose, wcT, o_rce);
        hipLaunchKernelGGL(routing_kernel, dim3(BB), dim3(64), 0, stream,
                           o_rce, o_act, lncg, lncb, beta, o_q, o_cp, o_ca, o_rce, o_ce);
        hipLaunchKernelGGL(head_mfma, dim3(256), dim3(512), 0, stream,
                           o_ce, lnhg, lnhb, W1F, b1, W2, b2, o_logits);
    } else {
        hipLaunchKernelGGL(act_kernel_fb, dim3(BB), dim3(256), 0, stream,
                           z, lnag, lnab, Wa, ba, o_act);
        hipLaunchKernelGGL(pose_kernel, dim3(BB / 64, RR), dim3(256), 0, stream,
                           z, Wp, bp, o_pose);
        hipLaunchKernelGGL(votes_kernel, dim3(BB / 64, RR, 5), dim3(256), 0, stream,
                           o_pose, wc, o_rce);
        hipLaunchKernelGGL(routing_kernel, dim3(BB), dim3(64), 0, stream,
                           o_rce, o_act, lncg, lncb, beta, o_q, o_cp, o_ca, o_rce, o_ce);
        hipLaunchKernelGGL(head_kernel, dim3(BB * KK / 64), dim3(256), 0, stream,
                           o_ce, lnhg, lnhb, W1, b1, W2, b2, o_logits);
    }
}

// Round 6
// 313.361 us; speedup vs baseline: 1.0481x; 1.0481x over previous
//
#include <hip/hip_runtime.h>
#include <cstddef>

#define BB 4096
#define DIN 2048
#define RR 7
#define DP 128
#define KK 25
#define DC 16
#define NITERS 3
#define RKH (RR*KK*DC)   // 2800
#define RK  (RR*KK)      // 175
#define KH  (KK*DC)      // 400
#define HD  (RR*DC)      // 112
#define H4  (4*HD)       // 448
#define HEAD_TILES (BB*KK/128)  // 800

typedef __attribute__((ext_vector_type(8))) short bf16x8;
typedef __attribute__((ext_vector_type(4))) float f32x4;

__device__ __forceinline__ unsigned pk_bf16(float a, float b) {
    union { float f; unsigned u; } xa, xb;
    xa.f = a; xb.f = b;
    unsigned ua = (xa.u + 0x7FFFu + ((xa.u >> 16) & 1u)) >> 16;
    unsigned ub = (xb.u + 0x7FFFu + ((xb.u >> 16) & 1u)) >> 16;
    return (ua & 0xFFFFu) | (ub << 16);
}

__device__ __forceinline__ unsigned short bf16_1(float a) {
    union { float f; unsigned u; } xa; xa.f = a;
    return (unsigned short)((xa.u + 0x7FFFu + ((xa.u >> 16) & 1u)) >> 16);
}

// tanh-approx gelu as x * sigmoid(x*(1.5958 + 0.07136 x^2)); fast rcp, no div sequence.
__device__ __forceinline__ float gelu_fast(float x) {
    float u = x * __builtin_fmaf(x * x, 0.07135655f, 1.5957691f);
    u = fmaxf(u, -30.0f);
    float e = __expf(-u);
    return x * __builtin_amdgcn_rcpf(1.0f + e);
}

// ---------------------------------------------------------------------------
// Prep: transpose fp32 [RS][CS] -> bf16 [CS][RS].  (mid-tier only)
// ---------------------------------------------------------------------------
__global__ __launch_bounds__(256) void transpose_cvt_kernel(
    const float* __restrict__ src, unsigned short* __restrict__ dst, int RS, int CS)
{
    __shared__ float T[64][65];
    int r0 = blockIdx.x * 64, c0 = blockIdx.y * 64;
    size_t bo = (size_t)blockIdx.z * RS * CS;
    src += bo; dst += bo;
    int t = threadIdx.x;
    for (int s = t; s < 64 * 16; s += 256) {
        int row = s >> 4, c4 = s & 15;
        int gr = r0 + row, gc = c0 + c4 * 4;
        float4 v = make_float4(0.f, 0.f, 0.f, 0.f);
        if (gr < RS && gc < CS) v = *(const float4*)(src + (size_t)gr * CS + gc);
        T[row][c4 * 4 + 0] = v.x; T[row][c4 * 4 + 1] = v.y;
        T[row][c4 * 4 + 2] = v.z; T[row][c4 * 4 + 3] = v.w;
    }
    __syncthreads();
    for (int s = t; s < 64 * 16; s += 256) {
        int col = s >> 4, r4 = s & 15;
        int gc = c0 + col, gr = r0 + r4 * 4;
        if (gc < CS && gr + 3 < RS) {
            unsigned lo = pk_bf16(T[r4 * 4 + 0][col], T[r4 * 4 + 1][col]);
            unsigned hi = pk_bf16(T[r4 * 4 + 2][col], T[r4 * 4 + 3][col]);
            *(uint2*)(dst + (size_t)gc * RS + gr) = make_uint2(lo, hi);
        }
    }
}

// ---------------------------------------------------------------------------
// Prep: W1 frag (standalone, mid-tier).
// ---------------------------------------------------------------------------
__global__ __launch_bounds__(256) void w1_frag_kernel(
    const float* __restrict__ W1, unsigned short* __restrict__ W1F)
{
    int d = blockIdx.x * 256 + threadIdx.x;
    int e2 = d & 3;
    int lane = (d >> 2) & 63;
    int fid = d >> 8;
    int j = fid & 3, ks = (fid >> 2) & 3, nc = fid >> 4;
    int col = nc * 64 + j * 16 + (lane & 15);
    int k = ks * 32 + (lane >> 4) * 8 + e2 * 2;
    float a = (k < HD)     ? W1[(size_t)k * H4 + col]       : 0.f;
    float b = (k + 1 < HD) ? W1[(size_t)(k + 1) * H4 + col] : 0.f;
    ((unsigned*)W1F)[d] = pk_bf16(a, b);
}

// ---------------------------------------------------------------------------
// MERGED prep (top tier): one launch does wpf + w1f + wcf.
//   blockIdx.x in [0,896)     : W_prim -> wpf  (fragment-linear bf16)
//   blockIdx.x in [896,1008)  : W1     -> W1F  (fragment-linear, K-pad 128)
//   blockIdx.x in [1008,1183) : w_caps -> wcf  (fragment-linear)
// ---------------------------------------------------------------------------
__global__ __launch_bounds__(256) void prep_kernel(
    const float* __restrict__ Wp, unsigned short* __restrict__ wpf,
    const float* __restrict__ W1, unsigned short* __restrict__ W1F,
    const float* __restrict__ wc, unsigned short* __restrict__ wcf)
{
    __shared__ float Sw[128][17];
    int bx = blockIdx.x;
    int t = threadIdx.x;
    if (bx < 896) {
        int tid = bx * 256 + t;
        int lane = tid & 63;
        int CH = tid >> 6;
        int c = CH & 63, gcol = CH >> 6;
        int n = gcol * 16 + (lane & 15);
        int k0 = c * 32 + (lane >> 4) * 8;
        float a0 = Wp[(size_t)(k0 + 0) * (RR * DP) + n];
        float a1 = Wp[(size_t)(k0 + 1) * (RR * DP) + n];
        float a2 = Wp[(size_t)(k0 + 2) * (RR * DP) + n];
        float a3 = Wp[(size_t)(k0 + 3) * (RR * DP) + n];
        float a4 = Wp[(size_t)(k0 + 4) * (RR * DP) + n];
        float a5 = Wp[(size_t)(k0 + 5) * (RR * DP) + n];
        float a6 = Wp[(size_t)(k0 + 6) * (RR * DP) + n];
        float a7 = Wp[(size_t)(k0 + 7) * (RR * DP) + n];
        *(uint4*)(wpf + (size_t)tid * 8) =
            make_uint4(pk_bf16(a0, a1), pk_bf16(a2, a3), pk_bf16(a4, a5), pk_bf16(a6, a7));
    } else if (bx < 1008) {
        int d = (bx - 896) * 256 + t;
        int e2 = d & 3;
        int lane = (d >> 2) & 63;
        int fid = d >> 8;
        int j = fid & 3, ks = (fid >> 2) & 3, nc = fid >> 4;
        int col = nc * 64 + j * 16 + (lane & 15);
        int k = ks * 32 + (lane >> 4) * 8 + e2 * 2;
        float a = (k < HD)     ? W1[(size_t)k * H4 + col]       : 0.f;
        float b = (k + 1 < HD) ? W1[(size_t)(k + 1) * H4 + col] : 0.f;
        ((unsigned*)W1F)[d] = pk_bf16(a, b);
    } else {
        int idx = bx - 1008;
        int r = idx / 25, nt = idx % 25;
        {
            int d = t >> 1, half = t & 1;
            const float* sp = wc + ((size_t)r * DP + d) * KH + nt * 16 + half * 8;
            float4 v0 = *(const float4*)(sp);
            float4 v1 = *(const float4*)(sp + 4);
            Sw[d][half * 8 + 0] = v0.x; Sw[d][half * 8 + 1] = v0.y;
            Sw[d][half * 8 + 2] = v0.z; Sw[d][half * 8 + 3] = v0.w;
            Sw[d][half * 8 + 4] = v1.x; Sw[d][half * 8 + 5] = v1.y;
            Sw[d][half * 8 + 6] = v1.z; Sw[d][half * 8 + 7] = v1.w;
        }
        __syncthreads();
        int l = t >> 2, e2 = t & 3;
        int n = l & 15;
        unsigned* outp = (unsigned*)wcf;
#pragma unroll
        for (int c = 0; c < 4; ++c) {
            int d = c * 32 + (l >> 4) * 8 + e2 * 2;
            unsigned v = pk_bf16(Sw[d][n], Sw[d + 1][n]);
            outp[(size_t)((r * 100 + nt * 4 + c)) * 256 + t] = v;
        }
    }
}

// ---------------------------------------------------------------------------
// Kernel 1: act = clip(sigmoid(LN(z) @ W_act + b_act)); also emits zf.
// (round-4 measured version: two-pass LN, zf emit)
// ---------------------------------------------------------------------------
__global__ __launch_bounds__(256) void act_kernel(
    const float* __restrict__ z, const float* __restrict__ g, const float* __restrict__ bb,
    const float* __restrict__ Wa, const float* __restrict__ ba,
    float* __restrict__ act_out, unsigned short* __restrict__ zf_out)
{
    int b = blockIdx.x;
    int t = threadIdx.x;
    __shared__ float zs[DIN];
    __shared__ float ws1[4], ws2[4];
    __shared__ float wr[4][RR];
    const float* zr = z + (size_t)b * DIN;
    float s = 0.f, s2 = 0.f;
    for (int i = t; i < DIN; i += 256) {
        float v = zr[i]; zs[i] = v; s += v; s2 += v * v;
    }
    for (int off = 32; off; off >>= 1) { s += __shfl_down(s, off); s2 += __shfl_down(s2, off); }
    int w = t >> 6, lane = t & 63;
    if (lane == 0) { ws1[w] = s; ws2[w] = s2; }
    __syncthreads();
    if (zf_out) {
        int c = t >> 2, o = t & 3;
        const float* zp = zs + c * 32 + o * 8;
        unsigned d0 = pk_bf16(zp[0], zp[1]);
        unsigned d1 = pk_bf16(zp[2], zp[3]);
        unsigned d2 = pk_bf16(zp[4], zp[5]);
        unsigned d3 = pk_bf16(zp[6], zp[7]);
        size_t off2 = (((size_t)(b >> 4) * 64 + c) * 64 + (size_t)(o * 16 + (b & 15))) * 8;
        *(uint4*)(zf_out + off2) = make_uint4(d0, d1, d2, d3);
    }
    s  = ws1[0] + ws1[1] + ws1[2] + ws1[3];
    s2 = ws2[0] + ws2[1] + ws2[2] + ws2[3];
    float mean = s * (1.0f / DIN);
    float var  = s2 * (1.0f / DIN) - mean * mean;
    float rstd = rsqrtf(var + 1e-5f);
    float acc[RR];
#pragma unroll
    for (int r = 0; r < RR; ++r) acc[r] = 0.f;
    for (int i = t; i < DIN; i += 256) {
        float y = (zs[i] - mean) * rstd * g[i] + bb[i];
#pragma unroll
        for (int r = 0; r < RR; ++r) acc[r] += y * Wa[i * RR + r];
    }
    for (int off = 32; off; off >>= 1) {
#pragma unroll
        for (int r = 0; r < RR; ++r) acc[r] += __shfl_down(acc[r], off);
    }
    if (lane == 0) {
#pragma unroll
        for (int r = 0; r < RR; ++r) wr[w][r] = acc[r];
    }
    __syncthreads();
    if (t < RR) {
        float v = wr[0][t] + wr[1][t] + wr[2][t] + wr[3][t] + ba[t];
        float sg = 1.0f / (1.0f + expf(-v));
        sg = fminf(fmaxf(sg, 0.0f), 1.0f);
        act_out[(size_t)b * RR + t] = sg;
    }
}

// ---------------------------------------------------------------------------
// Kernel 2+3 FUSED (MFMA): pose = squash(zf @ wpf^T + bp);  u = pose_bf16 @ wc[r]
// ---------------------------------------------------------------------------
#define PV_STAGE(KS, AD, BD) do {                                                           \
    _Pragma("unroll")                                                                       \
    for (int q = 0; q < 4; ++q) {                                                           \
        int ch = w * 4 + q;                                                                 \
        int gi = ch >> 2, cc = ch & 3;                                                      \
        __builtin_amdgcn_global_load_lds(                                                   \
            (const __attribute__((address_space(1))) unsigned int*)(const void*)            \
                (zf + (((size_t)(zbase + gi) * 64) + (KS) * 4 + cc) * 512 + l * 8),         \
            (__attribute__((address_space(3))) unsigned int*)(void*)                        \
                ((AD) + ch * 512 + l * 8), 16, 0, 0);                                       \
        __builtin_amdgcn_global_load_lds(                                                   \
            (const __attribute__((address_space(1))) unsigned int*)(const void*)            \
                (wpf + (((size_t)(wbase + gi) * 64) + (KS) * 4 + cc) * 512 + l * 8),        \
            (__attribute__((address_space(3))) unsigned int*)(void*)                        \
                ((BD) + ch * 512 + l * 8), 16, 0, 0);                                       \
    }                                                                                       \
} while (0)

#define PV_COMPUTE(AD, BD) do {                                                             \
    _Pragma("unroll")                                                                       \
    for (int c = 0; c < 4; ++c) {                                                           \
        bf16x8 a[2], b[4];                                                                  \
        _Pragma("unroll")                                                                   \
        for (int i = 0; i < 2; ++i)                                                         \
            a[i] = *(const bf16x8*)((AD) + ((wrI * 2 + i) * 4 + c) * 512 + l * 8);          \
        _Pragma("unroll")                                                                   \
        for (int j = 0; j < 4; ++j)                                                         \
            b[j] = *(const bf16x8*)((BD) + ((wcI * 4 + j) * 4 + c) * 512 + l * 8);          \
        _Pragma("unroll")                                                                   \
        for (int i = 0; i < 2; ++i)                                                         \
            _Pragma("unroll")                                                               \
            for (int j = 0; j < 4; ++j)                                                     \
                acc[i][j] = __builtin_amdgcn_mfma_f32_16x16x32_bf16(a[i], b[j], acc[i][j], 0, 0, 0); \
    }                                                                                       \
} while (0)

__global__ __launch_bounds__(512) void pose_votes_mfma(
    const unsigned short* __restrict__ zf, const unsigned short* __restrict__ wpf,
    const unsigned short* __restrict__ wcf, const float* __restrict__ bp,
    float* __restrict__ pose_out, float* __restrict__ u_out)
{
    __shared__ __align__(16) char pool[135168];   // 132KB union
    __shared__ float sq[2][128];
    unsigned short* A0 = (unsigned short*)pool;
    unsigned short* A1 = (unsigned short*)(pool + 32768);
    unsigned short* B0 = (unsigned short*)(pool + 65536);
    unsigned short* B1 = (unsigned short*)(pool + 98304);
    unsigned short* AT = (unsigned short*)pool;
    unsigned short* BV = (unsigned short*)(pool + 32768);

    int m0 = blockIdx.x * 128, r = blockIdx.y;
    int t = threadIdx.x, w = t >> 6, l = t & 63;
    int wrI = w >> 1, wcI = w & 1;
    int lrow = l & 15, koff = l >> 4;
    int zbase = m0 >> 4;
    int wbase = r * 8;

    f32x4 acc[2][4];
#pragma unroll
    for (int i = 0; i < 2; ++i)
#pragma unroll
        for (int j = 0; j < 4; ++j) acc[i][j] = 0.0f;

    PV_STAGE(0, A0, B0);
    __syncthreads();
#pragma unroll 1
    for (int ks = 0; ks < 16; ks += 2) {
        if (ks + 1 < 16) PV_STAGE(ks + 1, A1, B1);
        PV_COMPUTE(A0, B0);
        __syncthreads();
        if (ks + 2 < 16) PV_STAGE(ks + 2, A0, B0);
        PV_COMPUTE(A1, B1);
        __syncthreads();
    }

    // ---- issue wcf DMA into BV ----
    const unsigned short* wrp = wcf + (size_t)r * 100 * 512;
#pragma unroll
    for (int q = 0; q < 13; ++q) {
        int chunk = w + q * 8;
        if (chunk < 100)
            __builtin_amdgcn_global_load_lds(
                (const __attribute__((address_space(1))) unsigned int*)(const void*)(wrp + (size_t)chunk * 512 + l * 8),
                (__attribute__((address_space(3))) unsigned int*)(void*)(BV + chunk * 512),
                16, 0, 0);
    }

    // ---- squash ----
    float bpv[4];
#pragma unroll
    for (int j = 0; j < 4; ++j) bpv[j] = bp[r * DP + wcI * 64 + j * 16 + lrow];
    float ns_[2][4];
#pragma unroll
    for (int i = 0; i < 2; ++i)
#pragma unroll
        for (int reg = 0; reg < 4; ++reg) {
            float ss = 0.f;
#pragma unroll
            for (int j = 0; j < 4; ++j) {
                float x = acc[i][j][reg] + bpv[j];
                acc[i][j][reg] = x;
                ss += x * x;
            }
            ss += __shfl_xor(ss, 1); ss += __shfl_xor(ss, 2);
            ss += __shfl_xor(ss, 4); ss += __shfl_xor(ss, 8);
            ns_[i][reg] = ss;
        }
    if (lrow == 0) {
#pragma unroll
        for (int i = 0; i < 2; ++i)
#pragma unroll
            for (int reg = 0; reg < 4; ++reg)
                sq[wcI][wrI * 32 + i * 16 + koff * 4 + reg] = ns_[i][reg];
    }
    __syncthreads();

#pragma unroll
    for (int i = 0; i < 2; ++i)
#pragma unroll
        for (int reg = 0; reg < 4; ++reg) {
            int rl = wrI * 32 + i * 16 + koff * 4 + reg;
            float ns = sq[0][rl] + sq[1][rl];
            float factor = (ns / fmaxf(1.0f + ns, 1e-6f)) / (sqrtf(ns) + 1e-6f);
            size_t rowbase = ((size_t)(m0 + rl) * RR + r) * DP;
            int g8 = rl >> 4, r15 = rl & 15;
#pragma unroll
            for (int j = 0; j < 4; ++j) {
                float v = acc[i][j][reg] * factor;
                int col = wcI * 64 + j * 16 + lrow;
                pose_out[rowbase + col] = v;
                int cseg = col >> 5;
                int l2 = r15 + 16 * ((col >> 3) & 3);
                AT[(size_t)((g8 * 4 + cseg) * 64 + l2) * 8 + (col & 7)] = bf16_1(v);
            }
        }
    __syncthreads();

    bf16x8 af2[4];
#pragma unroll
    for (int c = 0; c < 4; ++c)
        af2[c] = *(const bf16x8*)(AT + (size_t)((w * 4 + c) * 64 + l) * 8);
    int crow = (l >> 4) * 4;
#pragma unroll 1
    for (int nt = 0; nt < 25; ++nt) {
        f32x4 a2 = 0.0f;
#pragma unroll
        for (int c = 0; c < 4; ++c) {
            bf16x8 bfr = *(const bf16x8*)(BV + (size_t)((nt * 4 + c) * 64 + l) * 8);
            a2 = __builtin_amdgcn_mfma_f32_16x16x32_bf16(af2[c], bfr, a2, 0, 0, 0);
        }
#pragma unroll
        for (int reg = 0; reg < 4; ++reg) {
            int row = m0 + w * 16 + crow + reg;
            u_out[((size_t)row * RR + r) * KH + nt * 16 + (l & 15)] = a2[reg];
        }
    }
}

// ---------------------------------------------------------------------------
// Kernel 2 v1 (MFMA) — mid-tier fallback.
// ---------------------------------------------------------------------------
__global__ __launch_bounds__(256) void pose_mfma(
    const float* __restrict__ z, const unsigned short* __restrict__ WpT,
    const float* __restrict__ bp, float* __restrict__ pose_out)
{
    __shared__ __align__(16) unsigned short As[128 * 40];
    __shared__ __align__(16) unsigned short Bs[128 * 40];
    __shared__ float sq[2][128];
    int m0 = blockIdx.x * 128, r = blockIdx.y, t = threadIdx.x;
    int n0 = r * DP;
    int w = t >> 6, l = t & 63;
    int lrow = l & 15, koff = l >> 4;
    int rbase = (w >> 1) * 64, cbase = (w & 1) * 64;
    f32x4 acc[4][4];
#pragma unroll
    for (int i = 0; i < 4; ++i)
#pragma unroll
        for (int j = 0; j < 4; ++j) acc[i][j] = 0.0f;
    for (int kt = 0; kt < DIN; kt += 32) {
#pragma unroll
        for (int q = 0; q < 4; ++q) {
            int s = t + 256 * q;
            int row = s >> 3, k4 = s & 7;
            float4 v = *(const float4*)(z + (size_t)(m0 + row) * DIN + kt + k4 * 4);
            *(uint2*)(As + row * 40 + k4 * 4) = make_uint2(pk_bf16(v.x, v.y), pk_bf16(v.z, v.w));
        }
#pragma unroll
        for (int q = 0; q < 2; ++q) {
            int s = t + 256 * q;
            int col = s >> 2, k8 = s & 3;
            uint4 v = *(const uint4*)(WpT + (size_t)(n0 + col) * DIN + kt + k8 * 8);
            *(uint4*)(Bs + col * 40 + k8 * 8) = v;
        }
        __syncthreads();
        bf16x8 a[4], b[4];
#pragma unroll
        for (int i = 0; i < 4; ++i)
            a[i] = *(const bf16x8*)(As + (rbase + i * 16 + lrow) * 40 + koff * 8);
#pragma unroll
        for (int j = 0; j < 4; ++j)
            b[j] = *(const bf16x8*)(Bs + (cbase + j * 16 + lrow) * 40 + koff * 8);
#pragma unroll
        for (int i = 0; i < 4; ++i)
#pragma unroll
            for (int j = 0; j < 4; ++j)
                acc[i][j] = __builtin_amdgcn_mfma_f32_16x16x32_bf16(a[i], b[j], acc[i][j], 0, 0, 0);
        __syncthreads();
    }
    float bpv[4];
#pragma unroll
    for (int j = 0; j < 4; ++j) bpv[j] = bp[n0 + cbase + j * 16 + lrow];
    float ns_[4][4];
#pragma unroll
    for (int i = 0; i < 4; ++i)
#pragma unroll
        for (int reg = 0; reg < 4; ++reg) {
            float ss = 0.f;
#pragma unroll
            for (int j = 0; j < 4; ++j) {
                float x = acc[i][j][reg] + bpv[j];
                acc[i][j][reg] = x;
                ss += x * x;
            }
            ss += __shfl_xor(ss, 1); ss += __shfl_xor(ss, 2);
            ss += __shfl_xor(ss, 4); ss += __shfl_xor(ss, 8);
            ns_[i][reg] = ss;
        }
    if (lrow == 0) {
#pragma unroll
        for (int i = 0; i < 4; ++i)
#pragma unroll
            for (int reg = 0; reg < 4; ++reg)
                sq[w & 1][rbase + i * 16 + koff * 4 + reg] = ns_[i][reg];
    }
    __syncthreads();
#pragma unroll
    for (int i = 0; i < 4; ++i)
#pragma unroll
        for (int reg = 0; reg < 4; ++reg) {
            int rl = rbase + i * 16 + koff * 4 + reg;
            float ns = sq[0][rl] + sq[1][rl];
            float factor = (ns / fmaxf(1.0f + ns, 1e-6f)) / (sqrtf(ns) + 1e-6f);
            size_t rowbase = ((size_t)(m0 + rl) * RR + r) * DP;
#pragma unroll
            for (int j = 0; j < 4; ++j)
                pose_out[rowbase + cbase + j * 16 + lrow] = acc[i][j][reg] * factor;
        }
}

// ---------------------------------------------------------------------------
// Kernel 3 (MFMA) — mid-tier fallback.
// ---------------------------------------------------------------------------
__global__ __launch_bounds__(256) void votes_mfma(
    const float* __restrict__ pose, const unsigned short* __restrict__ wcT,
    float* __restrict__ u_out)
{
    __shared__ __align__(16) unsigned short As[128 * 152];
    __shared__ __align__(16) unsigned short Bs[80 * 152];
    int m0 = blockIdx.x * 128, r = blockIdx.y, n0 = blockIdx.z * 80;
    int t = threadIdx.x;
    int w = t >> 6, l = t & 63;
    int lrow = l & 15, koff = l >> 4;
    int rbase = w * 32;
#pragma unroll
    for (int q = 0; q < 16; ++q) {
        int s = t + 256 * q;
        int row = s >> 5, k4 = s & 31;
        float4 v = *(const float4*)(pose + ((size_t)(m0 + row) * RR + r) * DP + k4 * 4);
        *(uint2*)(As + row * 152 + k4 * 4) = make_uint2(pk_bf16(v.x, v.y), pk_bf16(v.z, v.w));
    }
    const unsigned short* wr_ = wcT + (size_t)r * KH * DP;
#pragma unroll
    for (int q = 0; q < 5; ++q) {
        int s = t + 256 * q;
        int col = s >> 4, k8 = s & 15;
        uint4 v = *(const uint4*)(wr_ + (size_t)(n0 + col) * DP + k8 * 8);
        *(uint4*)(Bs + col * 152 + k8 * 8) = v;
    }
    __syncthreads();
    f32x4 acc[2][5];
#pragma unroll
    for (int i = 0; i < 2; ++i)
#pragma unroll
        for (int j = 0; j < 5; ++j) acc[i][j] = 0.0f;
#pragma unroll
    for (int ks = 0; ks < 4; ++ks) {
        bf16x8 a[2], b[5];
#pragma unroll
        for (int i = 0; i < 2; ++i)
            a[i] = *(const bf16x8*)(As + (rbase + i * 16 + lrow) * 152 + ks * 32 + koff * 8);
#pragma unroll
        for (int j = 0; j < 5; ++j)
            b[j] = *(const bf16x8*)(Bs + (j * 16 + lrow) * 152 + ks * 32 + koff * 8);
#pragma unroll
        for (int i = 0; i < 2; ++i)
#pragma unroll
            for (int j = 0; j < 5; ++j)
                acc[i][j] = __builtin_amdgcn_mfma_f32_16x16x32_bf16(a[i], b[j], acc[i][j], 0, 0, 0);
    }
#pragma unroll
    for (int i = 0; i < 2; ++i)
#pragma unroll
        for (int reg = 0; reg < 4; ++reg) {
            int row = m0 + rbase + i * 16 + koff * 4 + reg;
            size_t base = ((size_t)row * RR + r) * KH + n0;
#pragma unroll
            for (int j = 0; j < 5; ++j)
                u_out[base + j * 16 + lrow] = acc[i][j][reg];
        }
}

// ---------------------------------------------------------------------------
// Kernel 4: routing — one wave per batch row b. (round-4 measured version)
// Note: 64-thread block => __syncthreads is single-wave (cheap).
// ---------------------------------------------------------------------------
__global__ __launch_bounds__(64) void routing_kernel(
    const float* __restrict__ u_in, const float* __restrict__ act_in,
    const float* __restrict__ lncg, const float* __restrict__ lncb,
    const float* __restrict__ beta_u,
    float* __restrict__ q_out, float* __restrict__ cp_out,
    float* __restrict__ ca_out, float* __restrict__ rce_out,
    float* __restrict__ ce_out)
{
    __shared__ __align__(16) float U[RKH];
    __shared__ float Q[RK];
    __shared__ float CP[KH];
    __shared__ float AG[RK];
    __shared__ float A7[RR];
    int b = blockIdx.x, t = threadIdx.x;
    const float4* u4 = (const float4*)(u_in + (size_t)b * RKH);
    float4* U4 = (float4*)U;
    for (int p = t; p < RKH / 4; p += 64) U4[p] = u4[p];
    if (t < RR) A7[t] = act_in[(size_t)b * RR + t];
    for (int p = t; p < RK; p += 64) Q[p] = 1.0f / KK;
    __syncthreads();
    for (int it = 0; it < NITERS; ++it) {
        for (int p = t; p < KH; p += 64) {
            int k = p / DC;
            float s = 0.f;
#pragma unroll
            for (int r = 0; r < RR; ++r) s += Q[r * KK + k] * A7[r] * U[r * KH + p];
            CP[p] = s;
        }
        __syncthreads();
        if (t < KK) {
            float m = 0.f;
#pragma unroll
            for (int h = 0; h < DC; ++h) m += CP[t * DC + h];
            m *= (1.0f / DC);
            float v = 0.f;
#pragma unroll
            for (int h = 0; h < DC; ++h) { float d = CP[t * DC + h] - m; v += d * d; }
            v *= (1.0f / DC);
            float rstd = rsqrtf(v + 1e-5f);
#pragma unroll
            for (int h = 0; h < DC; ++h)
                CP[t * DC + h] = (CP[t * DC + h] - m) * rstd * lncg[h] + lncb[h];
        }
        __syncthreads();
        for (int p = t; p < RK; p += 64) {
            int r = p / KK, k = p % KK;
            float s = 0.f;
#pragma unroll
            for (int h = 0; h < DC; ++h) s += CP[k * DC + h] * U[r * KH + k * DC + h];
            AG[p] = s * 0.25f;
        }
        __syncthreads();
        if (t < RR) {
            float mx = -1e30f;
            for (int k = 0; k < KK; ++k) mx = fmaxf(mx, AG[t * KK + k]);
            float e[KK], sum = 0.f;
            for (int k = 0; k < KK; ++k) { e[k] = expf(AG[t * KK + k] - mx); sum += e[k]; }
            float inv = 1.0f / sum;
            for (int k = 0; k < KK; ++k) Q[t * KK + k] = e[k] * inv;
        }
        __syncthreads();
    }
    if (t < KK) {
        float s = 0.f;
#pragma unroll
        for (int r = 0; r < RR; ++r) s += Q[r * KK + t] * A7[r];
        ca_out[(size_t)b * KK + t] = 1.0f / (1.0f + expf(-(beta_u[t] + s)));
    }
    for (int p = t; p < RK; p += 64) q_out[(size_t)b * RK + p] = Q[p];
    for (int p = t; p < KH; p += 64) cp_out[(size_t)b * KH + p] = CP[p];
    float4* rce4 = (float4*)(rce_out + (size_t)b * RKH);
    float4* ce4  = (float4*)ce_out;
    for (int p4 = t; p4 < RKH / 4; p4 += 64) {
        int base = p4 * 4;
        int r  = base / KH;
        int k  = (base % KH) / DC;
        int h0 = base % DC;
        float qv = Q[r * KK + k];
        float4 uv = U4[p4];
        float4 rv = make_float4(qv * uv.x, qv * uv.y, qv * uv.z, qv * uv.w);
        rce4[p4] = rv;
        size_t ci = ((size_t)b * RKH + (size_t)k * HD + (size_t)r * DC + h0) >> 2;
        ce4[ci] = rv;
    }
}

// ---------------------------------------------------------------------------
// Kernel 5 (MFMA): head — persistent blocks, 512 threads.
// ---------------------------------------------------------------------------
__global__ __launch_bounds__(512) void head_mfma(
    const float* __restrict__ ce, const float* __restrict__ g, const float* __restrict__ bb,
    const unsigned short* __restrict__ W1F, const float* __restrict__ b1,
    const float* __restrict__ W2, const float* __restrict__ b2,
    float* __restrict__ logits)
{
    __shared__ __align__(16) unsigned short As[128 * 128];
    __shared__ __align__(16) unsigned short Bs[448 * 128];
    __shared__ float LB1[H4];
    __shared__ float LW2[H4];
    int t = threadIdx.x;
    int w = t >> 6, l = t & 63;
    int lrow = l & 15, koff = l >> 4;

#pragma unroll
    for (int q = 0; q < 14; ++q) {
        int chunk = w * 14 + q;
        __builtin_amdgcn_global_load_lds(
            (const __attribute__((address_space(1))) unsigned int*)(const void*)(W1F + (size_t)chunk * 512 + l * 8),
            (__attribute__((address_space(3))) unsigned int*)(void*)(Bs + chunk * 512),
            16, 0, 0);
    }
    if (t >= 256) {
        for (int s = t - 256; s < H4; s += 256) { LB1[s] = b1[s]; LW2[s] = W2[s]; }
    }
    float b2v = b2[0];

    int row = t >> 1, half = t & 1;
    int lr = row & 15, rt = row >> 4;

    float4 v[14];
    int tile = blockIdx.x;
    if (t < 256 && tile < HEAD_TILES) {
        const float* rp = ce + (size_t)(tile * 128 + row) * HD + half * 56;
#pragma unroll
        for (int m = 0; m < 14; ++m) v[m] = *(const float4*)(rp + m * 4);
    }

    bool first = true;
    for (; tile < HEAD_TILES; tile += 256) {
        if (!first) __syncthreads();
        first = false;

        if (t < 256) {
            float s1 = 0.f, s2 = 0.f;
#pragma unroll
            for (int m = 0; m < 14; ++m) {
                s1 += v[m].x + v[m].y + v[m].z + v[m].w;
                s2 += v[m].x * v[m].x + v[m].y * v[m].y + v[m].z * v[m].z + v[m].w * v[m].w;
            }
            s1 += __shfl_xor(s1, 1); s2 += __shfl_xor(s2, 1);
            float mean = s1 * (1.0f / HD);
            float var  = s2 * (1.0f / HD) - mean * mean;
            float rstd = rsqrtf(var + 1e-5f);
#pragma unroll
            for (int j = 0; j < 7; ++j) {
                float4 gl0 = *(const float4*)(g  + half * 56 + j * 8);
                float4 gl1 = *(const float4*)(g  + half * 56 + j * 8 + 4);
                float4 bl0 = *(const float4*)(bb + half * 56 + j * 8);
                float4 bl1 = *(const float4*)(bb + half * 56 + j * 8 + 4);
                float4 x0 = v[j * 2], x1 = v[j * 2 + 1];
                float y0 = (x0.x - mean) * rstd * gl0.x + bl0.x;
                float y1 = (x0.y - mean) * rstd * gl0.y + bl0.y;
                float y2 = (x0.z - mean) * rstd * gl0.z + bl0.z;
                float y3 = (x0.w - mean) * rstd * gl0.w + bl0.w;
                float y4 = (x1.x - mean) * rstd * gl1.x + bl1.x;
                float y5 = (x1.y - mean) * rstd * gl1.y + bl1.y;
                float y6 = (x1.z - mean) * rstd * gl1.z + bl1.z;
                float y7 = (x1.w - mean) * rstd * gl1.w + bl1.w;
                int k8 = half * 7 + j;
                int ks = k8 >> 2, ko = k8 & 3;
                unsigned* dst = (unsigned*)(As + (size_t)((rt * 4 + ks) * 64 + ko * 16 + lr) * 8);
                dst[0] = pk_bf16(y0, y1); dst[1] = pk_bf16(y2, y3);
                dst[2] = pk_bf16(y4, y5); dst[3] = pk_bf16(y6, y7);
            }
            if (half) {
                uint4 z4 = make_uint4(0, 0, 0, 0);
                *(uint4*)(As + (size_t)((rt * 4 + 3) * 64 + 2 * 16 + lr) * 8) = z4;
                *(uint4*)(As + (size_t)((rt * 4 + 3) * 64 + 3 * 16 + lr) * 8) = z4;
            }
        }
        __syncthreads();

        bf16x8 af[4];
#pragma unroll
        for (int ks = 0; ks < 4; ++ks)
            af[ks] = *(const bf16x8*)(As + (size_t)((w * 4 + ks) * 64 + l) * 8);

        if (t < 256 && tile + 256 < HEAD_TILES) {
            const float* rp = ce + (size_t)((tile + 256) * 128 + row) * HD + half * 56;
#pragma unroll
            for (int m = 0; m < 14; ++m) v[m] = *(const float4*)(rp + m * 4);
        }

        float logitAcc[4];
#pragma unroll
        for (int reg = 0; reg < 4; ++reg) logitAcc[reg] = 0.f;

        for (int nc = 0; nc < 7; ++nc) {
            float b1v[4], w2v[4];
#pragma unroll
            for (int j = 0; j < 4; ++j) {
                b1v[j] = LB1[nc * 64 + j * 16 + lrow];
                w2v[j] = LW2[nc * 64 + j * 16 + lrow];
            }
            f32x4 acc[4];
#pragma unroll
            for (int j = 0; j < 4; ++j) acc[j] = 0.0f;
#pragma unroll
            for (int ks = 0; ks < 4; ++ks) {
                bf16x8 bfr[4];
#pragma unroll
                for (int j = 0; j < 4; ++j)
                    bfr[j] = *(const bf16x8*)(Bs + (size_t)(((nc * 4 + ks) * 4 + j) * 64 + l) * 8);
#pragma unroll
                for (int j = 0; j < 4; ++j)
                    acc[j] = __builtin_amdgcn_mfma_f32_16x16x32_bf16(af[ks], bfr[j], acc[j], 0, 0, 0);
            }
#pragma unroll
            for (int reg = 0; reg < 4; ++reg) {
                float sum = 0.f;
#pragma unroll
                for (int j = 0; j < 4; ++j) {
                    float x = acc[j][reg] + b1v[j];
                    sum += gelu_fast(x) * w2v[j];
                }
                logitAcc[reg] += sum;
            }
        }
#pragma unroll
        for (int reg = 0; reg < 4; ++reg) {
            float vv = logitAcc[reg];
            vv += __shfl_xor(vv, 1); vv += __shfl_xor(vv, 2);
            vv += __shfl_xor(vv, 4); vv += __shfl_xor(vv, 8);
            if (lrow == 0)
                logits[(size_t)tile * 128 + w * 16 + koff * 4 + reg] = vv + b2v;
        }
    }
}

// ===========================================================================
// Fallback fp32 kernels (lowest tier).
// ===========================================================================
__global__ __launch_bounds__(256) void pose_kernel(
    const float* __restrict__ z, const float* __restrict__ Wp, const float* __restrict__ bp,
    float* __restrict__ pose_out)
{
    __shared__ __align__(16) float As[64 * 36];
    __shared__ __align__(16) float Bs[32 * 128];
    int m0 = blockIdx.x * 64;
    int r  = blockIdx.y;
    int n0 = r * DP;
    int t  = threadIdx.x;
    int rg = t >> 5;
    int cg = t & 31;
    float acc[8][4] = {};
    for (int kt = 0; kt < DIN; kt += 32) {
#pragma unroll
        for (int q = 0; q < 2; ++q) {
            int s = t * 2 + q;
            int row = s >> 3, k4 = s & 7;
            float4 v = *(const float4*)(z + (size_t)(m0 + row) * DIN + kt + k4 * 4);
            *(float4*)(As + row * 36 + k4 * 4) = v;
        }
#pragma unroll
        for (int q = 0; q < 4; ++q) {
            int s = t + 256 * q;
            int row = s >> 5, c4 = s & 31;
            float4 v = *(const float4*)(Wp + (size_t)(kt + row) * (RR * DP) + n0 + c4 * 4);
            *(float4*)(Bs + row * 128 + c4 * 4) = v;
        }
        __syncthreads();
#pragma unroll
        for (int kk = 0; kk < 32; ++kk) {
            float4 bv = *(const float4*)(Bs + kk * 128 + cg * 4);
#pragma unroll
            for (int j = 0; j < 8; ++j) {
                float a = As[(rg * 8 + j) * 36 + kk];
                acc[j][0] += a * bv.x; acc[j][1] += a * bv.y;
                acc[j][2] += a * bv.z; acc[j][3] += a * bv.w;
            }
        }
        __syncthreads();
    }
    float bi0 = bp[n0 + cg * 4], bi1 = bp[n0 + cg * 4 + 1];
    float bi2 = bp[n0 + cg * 4 + 2], bi3 = bp[n0 + cg * 4 + 3];
#pragma unroll
    for (int j = 0; j < 8; ++j) {
        float x0 = acc[j][0] + bi0, x1 = acc[j][1] + bi1;
        float x2 = acc[j][2] + bi2, x3 = acc[j][3] + bi3;
        float ns = x0 * x0 + x1 * x1 + x2 * x2 + x3 * x3;
        for (int off = 1; off < 32; off <<= 1) ns += __shfl_xor(ns, off);
        float factor = (ns / fmaxf(1.0f + ns, 1e-6f)) / (sqrtf(ns) + 1e-6f);
        int row = m0 + rg * 8 + j;
        float4 o = make_float4(x0 * factor, x1 * factor, x2 * factor, x3 * factor);
        *(float4*)(pose_out + ((size_t)row * RR + r) * DP + cg * 4) = o;
    }
}

__global__ __launch_bounds__(256) void votes_kernel(
    const float* __restrict__ pose, const float* __restrict__ wc,
    float* __restrict__ u_out)
{
    __shared__ float As[64 * 129];
    __shared__ __align__(16) float Bs[64 * 80];
    int m0 = blockIdx.x * 64;
    int r  = blockIdx.y;
    int n0 = blockIdx.z * 80;
    int t  = threadIdx.x;
    const size_t wbase = (size_t)r * DP * KH;
#pragma unroll
    for (int q = 0; q < 8; ++q) {
        int s = t + 256 * q;
        int row = s >> 5, d4 = s & 31;
        float4 v = *(const float4*)(pose + ((size_t)(m0 + row) * RR + r) * DP + d4 * 4);
        As[row * 129 + d4 * 4 + 0] = v.x;
        As[row * 129 + d4 * 4 + 1] = v.y;
        As[row * 129 + d4 * 4 + 2] = v.z;
        As[row * 129 + d4 * 4 + 3] = v.w;
    }
    int m4 = t >> 4, n5 = t & 15;
    float acc[4][5];
#pragma unroll
    for (int i = 0; i < 4; ++i)
#pragma unroll
        for (int j = 0; j < 5; ++j) acc[i][j] = 0.f;
    for (int kt = 0; kt < DP; kt += 64) {
        __syncthreads();
#pragma unroll
        for (int q = 0; q < 5; ++q) {
            int s = t + 256 * q;
            int d = s / 20, c4 = s % 20;
            float4 v = *(const float4*)(wc + wbase + (size_t)(kt + d) * KH + n0 + c4 * 4);
            *(float4*)(Bs + d * 80 + c4 * 4) = v;
        }
        __syncthreads();
#pragma unroll 4
        for (int dd = 0; dd < 64; ++dd) {
            int d = kt + dd;
            float b_[5];
#pragma unroll
            for (int j = 0; j < 5; ++j) b_[j] = Bs[dd * 80 + n5 * 5 + j];
#pragma unroll
            for (int i = 0; i < 4; ++i) {
                float a = As[(m4 * 4 + i) * 129 + d];
#pragma unroll
                for (int j = 0; j < 5; ++j) acc[i][j] += a * b_[j];
            }
        }
    }
#pragma unroll
    for (int i = 0; i < 4; ++i) {
        int row = m0 + m4 * 4 + i;
        size_t base = ((size_t)row * RR + r) * KH + n0 + n5 * 5;
#pragma unroll
        for (int j = 0; j < 5; ++j) u_out[base + j] = acc[i][j];
    }
}

__global__ __launch_bounds__(256) void head_kernel(
    const float* __restrict__ ce, const float* __restrict__ g, const float* __restrict__ bb,
    const float* __restrict__ W1, const float* __restrict__ b1,
    const float* __restrict__ W2, const float* __restrict__ b2,
    float* __restrict__ logits)
{
    __shared__ __align__(16) float Y[64 * HD];
    __shared__ float Wc[HD * 64];
    __shared__ float Lg[64];
    int row0 = blockIdx.x * 64;
    int t = threadIdx.x;
    for (int s = t; s < 64 * HD; s += 256) Y[s] = ce[(size_t)row0 * HD + s];
    __syncthreads();
    if (t < 64) {
        float m = 0.f;
        for (int i = 0; i < HD; ++i) m += Y[t * HD + i];
        m *= (1.0f / HD);
        float v = 0.f;
        for (int i = 0; i < HD; ++i) { float d = Y[t * HD + i] - m; v += d * d; }
        v *= (1.0f / HD);
        float rstd = rsqrtf(v + 1e-5f);
        for (int i = 0; i < HD; ++i) Y[t * HD + i] = (Y[t * HD + i] - m) * rstd * g[i] + bb[i];
    }
    int rg = t >> 4;
    int cg = t & 15;
    float accRow[4] = {0.f, 0.f, 0.f, 0.f};
    for (int c0 = 0; c0 < H4; c0 += 64) {
        __syncthreads();
        for (int s = t; s < HD * 64; s += 256) {
            int i = s >> 6, c = s & 63;
            Wc[i * 64 + c] = W1[(size_t)i * H4 + c0 + c];
        }
        __syncthreads();
        float b1v[4], w2v[4];
#pragma unroll
        for (int c = 0; c < 4; ++c) { b1v[c] = b1[c0 + cg * 4 + c]; w2v[c] = W2[c0 + cg * 4 + c]; }
        float s_[4][4];
#pragma unroll
        for (int rr = 0; rr < 4; ++rr)
#pragma unroll
            for (int c = 0; c < 4; ++c) s_[rr][c] = b1v[c];
        for (int i4 = 0; i4 < HD / 4; ++i4) {
            float4 y4[4];
#pragma unroll
            for (int rr = 0; rr < 4; ++rr)
                y4[rr] = *(const float4*)(Y + (rg * 4 + rr) * HD + i4 * 4);
#pragma unroll
            for (int is = 0; is < 4; ++is) {
                float w_[4];
#pragma unroll
                for (int c = 0; c < 4; ++c) w_[c] = Wc[(i4 * 4 + is) * 64 + cg * 4 + c];
#pragma unroll
                for (int rr = 0; rr < 4; ++rr) {
                    float yv = (is == 0) ? y4[rr].x : (is == 1) ? y4[rr].y : (is == 2) ? y4[rr].z : y4[rr].w;
#pragma unroll
                    for (int c = 0; c < 4; ++c) s_[rr][c] += yv * w_[c];
                }
            }
        }
#pragma unroll
        for (int rr = 0; rr < 4; ++rr) {
#pragma unroll
            for (int c = 0; c < 4; ++c) {
                float x = s_[rr][c];
                float ge = 0.5f * x * (1.0f + erff(x * 0.70710678118654752440f));
                accRow[rr] += ge * w2v[c];
            }
        }
    }
#pragma unroll
    for (int rr = 0; rr < 4; ++rr) {
        float v = accRow[rr];
        v += __shfl_xor(v, 1); v += __shfl_xor(v, 2);
        v += __shfl_xor(v, 4); v += __shfl_xor(v, 8);
        if (cg == 0) Lg[rg * 4 + rr] = v;
    }
    __syncthreads();
    if (t < 64) logits[row0 + t] = Lg[t] + b2[0];
}

// ---------------------------------------------------------------------------
extern "C" void kernel_launch(void* const* d_in, const int* in_sizes, int n_in,
                              void* d_out, int out_size, void* d_ws, size_t ws_size,
                              hipStream_t stream) {
    const float* z    = (const float*)d_in[0];
    const float* Wp   = (const float*)d_in[1];
    const float* bp   = (const float*)d_in[2];
    const float* lnag = (const float*)d_in[3];
    const float* lnab = (const float*)d_in[4];
    const float* Wa   = (const float*)d_in[5];
    const float* ba   = (const float*)d_in[6];
    const float* wc   = (const float*)d_in[7];
    const float* lncg = (const float*)d_in[8];
    const float* lncb = (const float*)d_in[9];
    const float* beta = (const float*)d_in[10];
    const float* lnhg = (const float*)d_in[11];
    const float* lnhb = (const float*)d_in[12];
    const float* W1   = (const float*)d_in[13];
    const float* b1   = (const float*)d_in[14];
    const float* W2   = (const float*)d_in[15];
    const float* b2   = (const float*)d_in[16];

    float* out = (float*)d_out;
    float* o_logits = out;
    float* o_ce   = o_logits + (size_t)BB * KK;
    float* o_cp   = o_ce   + (size_t)BB * KK * HD;
    float* o_ca   = o_cp   + (size_t)BB * KK * DC;
    float* o_q    = o_ca   + (size_t)BB * KK;
    float* o_pose = o_q    + (size_t)BB * RK;
    float* o_act  = o_pose + (size_t)BB * RR * DP;
    float* o_rce  = o_act  + (size_t)BB * RR;

    // workspace layout: [W1F | wcf/wcT | zf | wpf]
    const size_t W1F_ELE = (size_t)H4 * 128;              // 57344
    const size_t WCF_ELE = (size_t)RR * 100 * 512;        // 358400
    const size_t ZF_ELE  = (size_t)BB * DIN;              // 8388608
    const size_t WPF_ELE = (size_t)(RR * DP) * DIN;       // 1835008
    unsigned short* W1F = (unsigned short*)d_ws;
    unsigned short* wcf = W1F + W1F_ELE;
    unsigned short* zf  = wcf + WCF_ELE;
    unsigned short* wpf = zf + ZF_ELE;
    unsigned short* wcT = wcf;   // mid-tier alias
    unsigned short* WpT = zf;    // mid-tier alias

    const size_t WS_NEW = (W1F_ELE + WCF_ELE + ZF_ELE + WPF_ELE) * sizeof(unsigned short);
    const size_t WS_MID = (W1F_ELE + WCF_ELE + WPF_ELE) * sizeof(unsigned short);

    if (ws_size >= WS_NEW) {
        hipLaunchKernelGGL(prep_kernel, dim3(1183), dim3(256), 0, stream,
                           Wp, wpf, W1, W1F, wc, wcf);
        hipLaunchKernelGGL(act_kernel, dim3(BB), dim3(256), 0, stream,
                           z, lnag, lnab, Wa, ba, o_act, zf);
        hipLaunchKernelGGL(pose_votes_mfma, dim3(BB / 128, RR), dim3(512), 0, stream,
                           zf, wpf, wcf, bp, o_pose, o_rce);
        hipLaunchKernelGGL(routing_kernel, dim3(BB), dim3(64), 0, stream,
                           o_rce, o_act, lncg, lncb, beta, o_q, o_cp, o_ca, o_rce, o_ce);
        hipLaunchKernelGGL(head_mfma, dim3(256), dim3(512), 0, stream,
                           o_ce, lnhg, lnhb, W1F, b1, W2, b2, o_logits);
    } else if (ws_size >= WS_MID) {
        hipLaunchKernelGGL(act_kernel, dim3(BB), dim3(256), 0, stream,
                           z, lnag, lnab, Wa, ba, o_act, (unsigned short*)nullptr);
        hipLaunchKernelGGL(transpose_cvt_kernel, dim3(DIN / 64, (RR * DP) / 64, 1), dim3(256), 0, stream,
                           Wp, WpT, DIN, RR * DP);
        hipLaunchKernelGGL(w1_frag_kernel, dim3(112), dim3(256), 0, stream, W1, W1F);
        hipLaunchKernelGGL(transpose_cvt_kernel, dim3(2, 7, RR), dim3(256), 0, stream,
                           wc, wcT, DP, KH);
        hipLaunchKernelGGL(pose_mfma, dim3(BB / 128, RR), dim3(256), 0, stream,
                           z, WpT, bp, o_pose);
        hipLaunchKernelGGL(votes_mfma, dim3(BB / 128, RR, 5), dim3(256), 0, stream,
                           o_pose, wcT, o_rce);
        hipLaunchKernelGGL(routing_kernel, dim3(BB), dim3(64), 0, stream,
                           o_rce, o_act, lncg, lncb, beta, o_q, o_cp, o_ca, o_rce, o_ce);
        hipLaunchKernelGGL(head_mfma, dim3(256), dim3(512), 0, stream,
                           o_ce, lnhg, lnhb, W1F, b1, W2, b2, o_logits);
    } else {
        hipLaunchKernelGGL(act_kernel, dim3(BB), dim3(256), 0, stream,
                           z, lnag, lnab, Wa, ba, o_act, (unsigned short*)nullptr);
        hipLaunchKernelGGL(pose_kernel, dim3(BB / 64, RR), dim3(256), 0, stream,
                           z, Wp, bp, o_pose);
        hipLaunchKernelGGL(votes_kernel, dim3(BB / 64, RR, 5), dim3(256), 0, stream,
                           o_pose, wc, o_rce);
        hipLaunchKernelGGL(routing_kernel, dim3(BB), dim3(64), 0, stream,
                           o_rce, o_act, lncg, lncb, beta, o_q, o_cp, o_ca, o_rce, o_ce);
        hipLaunchKernelGGL(head_kernel, dim3(BB * KK / 64), dim3(256), 0, stream,
                           o_ce, lnhg, lnhb, W1, b1, W2, b2, o_logits);
    }
}